// Round 5
// baseline (630.278 us; speedup 1.0000x reference)
//
#include <hip/hip_runtime.h>

using u16 = unsigned short;
using u32 = unsigned int;

typedef float f32x4 __attribute__((ext_vector_type(4)));
typedef __bf16 bf16x8 __attribute__((ext_vector_type(8)));
typedef u16 u16x8 __attribute__((ext_vector_type(8)));

// ---------- helpers ----------
__device__ __forceinline__ u16 f2bf(float f){
  u32 u = __builtin_bit_cast(u32, f);
  u32 r = (u + 0x7fffu + ((u >> 16) & 1u)) >> 16;   // RNE
  return (u16)r;
}
__device__ __forceinline__ float bf2f(u16 h){
  u32 u = ((u32)h) << 16;
  return __builtin_bit_cast(float, u);
}
__device__ __forceinline__ void gl2lds16(const void* g, void* l){
  __builtin_amdgcn_global_load_lds((const __attribute__((address_space(1))) u32*)g,
                                   (__attribute__((address_space(3))) u32*)l, 16, 0, 0);
}
// 16B-chunk XOR swizzle within a row of 24 chunks (K rows, 192 elems)
__device__ __forceinline__ int swz24(int ck, int r){ return (ck & 24) | ((ck ^ r) & 7); }

// ---------- elementwise convert x ----------
__global__ __launch_bounds__(256) void cvt_f32_bf16(const float* __restrict__ in,
                                                    u16* __restrict__ out, long n){
  long i = ((long)blockIdx.x*256 + threadIdx.x)*4;
  if (i >= n) return;
  float4 v = *(const float4*)(in + i);
  u16 o[4] = { f2bf(v.x), f2bf(v.y), f2bf(v.z), f2bf(v.w) };
  *(ushort4*)(out + i) = *(ushort4*)o;
}

// ---------- weight transpose+convert: in fp32 [K][N] -> out bf16 [N][K] ----------
__global__ __launch_bounds__(256) void transpose_w(const float* __restrict__ in,
                                                   u16* __restrict__ out, int K, int N){
  __shared__ float tile[32][33];
  int n0 = blockIdx.x*32, k0 = blockIdx.y*32;
  int tx = threadIdx.x, ty = threadIdx.y;
  for (int i = ty; i < 32; i += 8)
    tile[i][tx] = in[(size_t)(k0+i)*N + n0+tx];
  __syncthreads();
  for (int i = ty; i < 32; i += 8)
    out[(size_t)(n0+i)*K + k0+tx] = f2bf(tile[tx][i]);
}

// ---------- rope tables (f64 trig) ----------
__global__ __launch_bounds__(256) void rope_tables(float* __restrict__ cosT, float* __restrict__ sinT){
  int idx = blockIdx.x*256 + threadIdx.x;   // 2048*32
  int t = idx >> 5, d = idx & 31;
  double inv = pow(10000.0, -(double)d / 32.0);
  double a = (double)t * inv;
  cosT[idx] = (float)cos(a);
  sinT[idx] = (float)sin(a);
}

// ---------- m97-style 128x128 bf16 MFMA GEMM, C = A[M][K] * Bt[N][K]^T ----------
template<int OUT_BF16>
__global__ __launch_bounds__(256) void gemm_bt(const u16* __restrict__ A,
                                               const u16* __restrict__ Bt,
                                               void* __restrict__ Cout,
                                               int M, int N, int K, float cscale){
  __shared__ u16 As[128*32];
  __shared__ u16 Bs[128*32];
  const int tid = threadIdx.x, lane = tid & 63, wave = tid >> 6;
  const int m0 = blockIdx.y*128, n0 = blockIdx.x*128;
  const int wm = (wave >> 1)*64, wn = (wave & 1)*64;
  const int g = lane >> 4, lr = lane & 15;
  f32x4 acc[4][4] = {};
  const int sr = (wave*2)*16 + (lane >> 2);      // staging row base for chunk i=0
  const int sc = (lane & 3)*8;                   // staging col
  for (int k0 = 0; k0 < K; k0 += 32){
    __syncthreads();
    #pragma unroll
    for (int i = 0; i < 2; i++){
      int c = wave*2 + i;
      int r = sr + i*16;
      gl2lds16(A  + (size_t)(m0+r)*K + k0 + sc, (char*)As + c*1024);
      gl2lds16(Bt + (size_t)(n0+r)*K + k0 + sc, (char*)Bs + c*1024);
    }
    __syncthreads();
    bf16x8 af[4], bfr[4];
    #pragma unroll
    for (int mi = 0; mi < 4; mi++) af[mi]  = *reinterpret_cast<const bf16x8*>(&As[(wm+mi*16+lr)*32 + g*8]);
    #pragma unroll
    for (int ni = 0; ni < 4; ni++) bfr[ni] = *reinterpret_cast<const bf16x8*>(&Bs[(wn+ni*16+lr)*32 + g*8]);
    #pragma unroll
    for (int mi = 0; mi < 4; mi++)
      #pragma unroll
      for (int ni = 0; ni < 4; ni++)
        acc[mi][ni] = __builtin_amdgcn_mfma_f32_16x16x32_bf16(af[mi], bfr[ni], acc[mi][ni], 0,0,0);
  }
  #pragma unroll
  for (int mi = 0; mi < 4; mi++)
    #pragma unroll
    for (int ni = 0; ni < 4; ni++)
      #pragma unroll
      for (int r = 0; r < 4; r++){
        int row = m0 + wm + mi*16 + g*4 + r;
        int col = n0 + wn + ni*16 + lr;
        float v = acc[mi][ni][r];
        if (OUT_BF16) ((u16*)Cout)[(size_t)row*N + col] = f2bf(v*cscale);
        else          ((float*)Cout)[(size_t)row*N + col] = v;
      }
}

// ---------- rmsnorm rows (fp32 in -> bf16 out) ----------
__global__ __launch_bounds__(256) void rmsnorm_kernel(const float* __restrict__ in,
                                                      const float* __restrict__ w,
                                                      u16* __restrict__ out, int ncols){
  int row = blockIdx.x;
  const float* x = in + (size_t)row*ncols;
  float ss = 0.f;
  for (int c = threadIdx.x; c < ncols; c += 256){ float v = x[c]; ss += v*v; }
  #pragma unroll
  for (int m = 1; m < 64; m <<= 1) ss += __shfl_xor(ss, m, 64);
  __shared__ float p[4];
  if ((threadIdx.x & 63) == 0) p[threadIdx.x >> 6] = ss;
  __syncthreads();
  float inv = rsqrtf((p[0]+p[1]+p[2]+p[3]) / (float)ncols + 1e-6f);
  u16* o = out + (size_t)row*ncols;
  for (int c = threadIdx.x; c < ncols; c += 256) o[c] = f2bf(x[c]*inv*w[c]);
}

// ---------- kv split: rmsnorm(first 512) -> kvlat ; rope(last 512) -> Kf rope cols ----------
__global__ __launch_bounds__(256) void kv_split_kernel(const float* __restrict__ kvraw,
                                                       const float* __restrict__ lnw,
                                                       const float* __restrict__ cosT,
                                                       const float* __restrict__ sinT,
                                                       u16* __restrict__ kvlat,
                                                       u16* __restrict__ Kf){
  int row = blockIdx.x;                       // 0..4095
  int t = row & 2047, b = row >> 11;
  const float* x = kvraw + (size_t)row*1024;
  float ss = 0.f;
  for (int c = threadIdx.x; c < 512; c += 256){ float v = x[c]; ss += v*v; }
  #pragma unroll
  for (int m = 1; m < 64; m <<= 1) ss += __shfl_xor(ss, m, 64);
  __shared__ float p[4];
  if ((threadIdx.x & 63) == 0) p[threadIdx.x >> 6] = ss;
  __syncthreads();
  float inv = rsqrtf((p[0]+p[1]+p[2]+p[3]) / 512.0f + 1e-6f);
  for (int c = threadIdx.x; c < 512; c += 256)
    kvlat[(size_t)row*512 + c] = f2bf(x[c]*inv*lnw[c]);
  // rope: 8 heads x 32 pairs = 256 threads exactly
  int kh = threadIdx.x >> 5, dp = threadIdx.x & 31;
  float x1 = x[512 + kh*64 + dp], x2 = x[512 + kh*64 + dp + 32];
  float cv = cosT[t*32 + dp], sv = sinT[t*32 + dp];
  float o1 = x1*cv - x2*sv;
  float o2 = x2*cv + x1*sv;
  u16* kr = Kf + ((size_t)(b*8 + kh)*2048 + t)*192;
  int c1 = 128 + dp, c2 = 128 + dp + 32;
  kr[(swz24(c1 >> 3, t) << 3) | (c1 & 7)] = f2bf(o1);
  kr[(swz24(c2 >> 3, t) << 3) | (c2 & 7)] = f2bf(o2);
}

// ---------- q rope in place on q bf16 [4096][3072] ----------
__global__ __launch_bounds__(256) void q_rope_kernel(u16* __restrict__ q,
                                                     const float* __restrict__ cosT,
                                                     const float* __restrict__ sinT){
  int idx = blockIdx.x*256 + threadIdx.x;     // 4096*16*32
  int row = idx >> 9, rem = idx & 511;
  int h = rem >> 5, dp = rem & 31;
  int t = row & 2047;
  u16* pq = q + (size_t)row*3072 + h*192 + 128;
  float x1 = bf2f(pq[dp]), x2 = bf2f(pq[dp+32]);
  float cv = cosT[t*32 + dp], sv = sinT[t*32 + dp];
  pq[dp]    = f2bf(x1*cv - x2*sv);
  pq[dp+32] = f2bf(x2*cv + x1*sv);
}

// ---------- k_nope copy (16B chunks, swizzled) ----------
__global__ __launch_bounds__(256) void knope_kernel(const u16* __restrict__ kv,
                                                    u16* __restrict__ Kf){
  int idx = blockIdx.x*256 + threadIdx.x;     // 4096*8*16
  int row = idx >> 7, rem = idx & 127;
  int kh = rem >> 4, ck = rem & 15;
  int t = row & 2047, b = row >> 11;
  int ck2 = (ck & 8) | ((ck ^ t) & 7);
  uint4 v = *(const uint4*)(kv + (size_t)row*2048 + kh*256 + ck*8);
  *(uint4*)(Kf + ((size_t)(b*8 + kh)*2048 + t)*192 + ck2*8) = v;
}

// ---------- V transpose: kv[row][kvh*256+128+vd] -> V2[b][kvh][tchunk][vd][8t] ----------
__global__ __launch_bounds__(256) void v_transpose(const u16* __restrict__ kv,
                                                   u16* __restrict__ vT){
  int bid = blockIdx.x;                        // 2*8*32
  int tt = bid & 31, kvh = (bid >> 5) & 7, b = bid >> 8;
  int t0 = tt*64;
  __shared__ u16 tile[64][136];
  int tid = threadIdx.x;
  #pragma unroll
  for (int i = 0; i < 4; i++){
    int c = tid + i*256;                       // 1024 chunks of 8 elems
    int r = c >> 4, ck = c & 15;
    const u16* src = kv + ((size_t)(b*2048 + t0 + r))*2048 + kvh*256 + 128 + ck*8;
    *(uint4*)&tile[r][ck*8] = *(const uint4*)src;
  }
  __syncthreads();
  u16* dst = vT + ((size_t)(b*8 + kvh)*256 + (t0 >> 3))*1024;
  #pragma unroll
  for (int i = 0; i < 4; i++){
    int c = tid + i*256;                       // tci(0..7) x vd(0..127)
    int vd = c & 127, tci = c >> 7;
    uint4 tv;
    u16* tp = (u16*)&tv;
    #pragma unroll
    for (int j = 0; j < 8; j++) tp[j] = tile[tci*8 + j][vd];
    *(uint4*)(dst + ((size_t)tci*128 + vd)*8) = tv;
  }
}

// ---------- flash attention: XCD-grouped, single-K LDS pipeline, V direct from (XCD-local) L2 ----------
// Q is PRE-SCALED by 192^-0.5 (folded into q_b gemm epilogue).
__global__ __launch_bounds__(256, 4) void attn_kernel(const u16* __restrict__ Q,
                                                      const u16* __restrict__ Kf,
                                                      const u16* __restrict__ Vt,
                                                      u16* __restrict__ Oa){
  constexpr int T = 2048;
  constexpr int NT = T/64;
  __shared__ u16 Ks[64*192];       // 24KB single buffer
  __shared__ u16 Ps[4][1024];      // 8KB
  const int tid = threadIdx.x, lane = tid & 63, wave = tid >> 6;
  const int g = lane >> 4, lr = lane & 15;

  // bijective XCD swizzle: all 64 blocks of one (b,kvh) group land on one XCD
  const int wg = blockIdx.x;                 // 0..1023
  const int role = (wg & 7)*128 + (wg >> 3); // xcd*128 + slot
  const int grp = role >> 6;                 // b*8 + kvh
  const int b = grp >> 3, kvh = grp & 7;
  const int within = role & 63;
  const int h = kvh*2 + (within >> 5);
  const int q0 = (within & 31)*64 + wave*16;

  bf16x8 aq[6];
  {
    const u16* qrow = Q + ((size_t)b*T + q0 + lr)*3072 + h*192;
    #pragma unroll
    for (int kc = 0; kc < 6; kc++)
      aq[kc] = *reinterpret_cast<const bf16x8*>(qrow + kc*32 + g*8);
  }
  const u16* Kbase = Kf + (size_t)(b*8 + kvh)*T*192;
  const u16* Vbase = Vt + (size_t)(b*8 + kvh)*262144;   // [tchunk][vd][8]

  // ones B-fragment (col 0 of B = 1.0) for row-sum-via-MFMA
  u16x8 onesb_u = {};
  #pragma unroll
  for (int j = 0; j < 8; j++) onesb_u[j] = (lr == 0) ? (u16)0x3F80 : (u16)0;
  const bf16x8 ones_b = __builtin_bit_cast(bf16x8, onesb_u);

  f32x4 ovb[8] = {};
  float mrow[4] = {-1e30f,-1e30f,-1e30f,-1e30f};
  float lp[4] = {};              // row-sum partials, MFMA-D layout (valid at lr==0)

  auto stageK = [&](int kt){
    const u16* ksrc = Kbase + (size_t)kt*12288 + wave*3072 + lane*8;
    #pragma unroll
    for (int i = 0; i < 6; i++)
      gl2lds16(ksrc + i*512, (char*)Ks + (wave*6 + i)*1024);
  };

  stageK(0);
  __syncthreads();               // vmcnt(0) drain: K tile 0 ready

  for (int kt = 0; kt < NT; kt++){
    const bool notlast = (kt + 1 < NT);

    // ---- QK^T (Q pre-scaled) ----
    f32x4 s[4];
    __builtin_amdgcn_s_setprio(1);
    #pragma unroll
    for (int nb = 0; nb < 4; nb++){
      const int row = nb*16 + lr;
      f32x4 a = {0.f,0.f,0.f,0.f};
      #pragma unroll
      for (int kc = 0; kc < 6; kc++){
        int ckl = swz24(kc*4 + g, row);
        bf16x8 kf = *reinterpret_cast<const bf16x8*>(&Ks[row*192 + ckl*8]);
        a = __builtin_amdgcn_mfma_f32_16x16x32_bf16(aq[kc], kf, a, 0,0,0);
      }
      s[nb] = a;
    }
    __builtin_amdgcn_s_setprio(0);

    // barrier_A: all waves done reading Ks. lgkm-only.
    asm volatile("s_waitcnt lgkmcnt(0)" ::: "memory");
    __builtin_amdgcn_s_barrier();
    __builtin_amdgcn_sched_barrier(0);
    if (notlast) stageK(kt + 1);   // DMA next K into same buffer; hidden under softmax+PV

    // ---- softmax: defer-max THR=8 ----
    float tmax[4];
    #pragma unroll
    for (int r = 0; r < 4; r++){
      float v = fmaxf(fmaxf(s[0][r], s[1][r]), fmaxf(s[2][r], s[3][r]));
      v = fmaxf(v, __shfl_xor(v, 1, 64));
      v = fmaxf(v, __shfl_xor(v, 2, 64));
      v = fmaxf(v, __shfl_xor(v, 4, 64));
      v = fmaxf(v, __shfl_xor(v, 8, 64));
      tmax[r] = v;
    }
    int ok = (tmax[0] <= mrow[0] + 8.f) & (tmax[1] <= mrow[1] + 8.f) &
             (tmax[2] <= mrow[2] + 8.f) & (tmax[3] <= mrow[3] + 8.f);
    if (!__all(ok)){
      #pragma unroll
      for (int r = 0; r < 4; r++){
        float mn = fmaxf(mrow[r], tmax[r]);
        float corr = __expf(mrow[r] - mn);
        mrow[r] = mn;
        lp[r] *= corr;
        #pragma unroll
        for (int vb = 0; vb < 8; vb++) ovb[vb][r] *= corr;
      }
    }
    #pragma unroll
    for (int nb = 0; nb < 4; nb++)
      #pragma unroll
      for (int r = 0; r < 4; r++){
        float pv = __expf(s[nb][r] - mrow[r]);
        int prow = g*4 + r, col = nb*16 + lr;
        int ck = (col >> 3) ^ (prow & 7);
        Ps[wave][prow*64 + ck*8 + (col & 7)] = f2bf(pv);
      }

    // wave-local LDS write->read fence (Ps is per-wave private)
    asm volatile("s_waitcnt lgkmcnt(0)" ::: "memory");
    __builtin_amdgcn_sched_barrier(0);

    // ---- PV: P from LDS, V direct from XCD-local L2; row-sum via ones-MFMA ----
    bf16x8 ap[2];
    #pragma unroll
    for (int k2 = 0; k2 < 2; k2++){
      int ck = (k2*4 + g) ^ (lr & 7);
      ap[k2] = *reinterpret_cast<const bf16x8*>(&Ps[wave][lr*64 + ck*8]);
    }
    {
      f32x4 ts = {0.f,0.f,0.f,0.f};
      ts = __builtin_amdgcn_mfma_f32_16x16x32_bf16(ap[0], ones_b, ts, 0,0,0);
      ts = __builtin_amdgcn_mfma_f32_16x16x32_bf16(ap[1], ones_b, ts, 0,0,0);
      #pragma unroll
      for (int r = 0; r < 4; r++) lp[r] += ts[r];
    }
    __builtin_amdgcn_s_setprio(1);
    #pragma unroll
    for (int vb = 0; vb < 8; vb++){
      #pragma unroll
      for (int k2 = 0; k2 < 2; k2++){
        const uint4* vsrc = (const uint4*)(Vbase + ((size_t)(kt*8 + k2*4 + g)*128 + vb*16 + lr)*8);
        bf16x8 bv = __builtin_bit_cast(bf16x8, *vsrc);
        ovb[vb] = __builtin_amdgcn_mfma_f32_16x16x32_bf16(ap[k2], bv, ovb[vb], 0,0,0);
      }
    }
    __builtin_amdgcn_s_setprio(0);

    if (notlast) __syncthreads();  // vmcnt(0)+lgkm: staged K complete; all waves synced
  }

  // ---- epilogue: broadcast row-sums from lr==0 lanes, normalize, store ----
  float inv[4];
  #pragma unroll
  for (int r = 0; r < 4; r++){
    float sum = __shfl(lp[r], lane & 48, 64);
    inv[r] = 1.0f / sum;
  }
  u16* obase = Oa + ((size_t)b*T + q0)*2048 + h*128;
  #pragma unroll
  for (int vb = 0; vb < 8; vb++)
    #pragma unroll
    for (int r = 0; r < 4; r++)
      obase[(size_t)(g*4 + r)*2048 + vb*16 + lr] = f2bf(ovb[vb][r]*inv[r]);
}

// ---------- launch ----------
extern "C" void kernel_launch(void* const* d_in, const int* in_sizes, int n_in,
                              void* d_out, int out_size, void* d_ws, size_t ws_size,
                              hipStream_t stream){
  const float* hs      = (const float*)d_in[0];
  const float* q_a_w   = (const float*)d_in[1];
  const float* q_a_ln  = (const float*)d_in[2];
  const float* q_b_w   = (const float*)d_in[3];
  const float* kv_a_w  = (const float*)d_in[4];
  const float* kv_a_ln = (const float*)d_in[5];
  const float* kv_b_w  = (const float*)d_in[6];
  const float* o_w     = (const float*)d_in[7];

  char* ws = (char*)d_ws;
  size_t off = 0;
  auto alloc = [&](size_t bytes){ void* p = ws + off; off += bytes; return p; };
  u16*  Wqa   = (u16*)alloc(1536ull*2048*2);
  u16*  Wqb   = (u16*)alloc(3072ull*1536*2);
  u16*  Wkva  = (u16*)alloc(1024ull*2048*2);
  u16*  Wkvb  = (u16*)alloc(2048ull*512*2);
  u16*  Wo    = (u16*)alloc(2048ull*2048*2);
  u16*  XB    = (u16*)alloc(4096ull*2048*2);      // x bf16 -> later attn output
  char* R2    = (char*)alloc(4096ull*1536*4);     // q_a fp32 -> later q bf16 [4096][3072]
  char* R3    = (char*)alloc(4096ull*1024*4);     // kv_raw fp32 -> later kv bf16 [4096][2048]
  u16*  Qlat  = (u16*)alloc(4096ull*1536*2);
  u16*  KVlat = (u16*)alloc(4096ull*512*2);
  u16*  Kf    = (u16*)alloc(2ull*8*2048*192*2);
  u16*  Vt    = (u16*)alloc(2ull*8*128*2048*2);
  float* cosT = (float*)alloc(2048ull*32*4);
  float* sinT = (float*)alloc(2048ull*32*4);
  (void)ws_size; (void)in_sizes; (void)n_in; (void)out_size;

  const float qscale = 0.07216878364870322f;      // 192^-0.5 folded into q_b gemm

  cvt_f32_bf16<<<8192, 256, 0, stream>>>(hs, XB, 4096ll*2048);
  transpose_w<<<dim3(1536/32, 2048/32), dim3(32,8), 0, stream>>>(q_a_w,  Wqa,  2048, 1536);
  transpose_w<<<dim3(3072/32, 1536/32), dim3(32,8), 0, stream>>>(q_b_w,  Wqb,  1536, 3072);
  transpose_w<<<dim3(1024/32, 2048/32), dim3(32,8), 0, stream>>>(kv_a_w, Wkva, 2048, 1024);
  transpose_w<<<dim3(2048/32,  512/32), dim3(32,8), 0, stream>>>(kv_b_w, Wkvb,  512, 2048);
  transpose_w<<<dim3(2048/32, 2048/32), dim3(32,8), 0, stream>>>(o_w,    Wo,   2048, 2048);
  rope_tables<<<256, 256, 0, stream>>>(cosT, sinT);

  gemm_bt<0><<<dim3(12, 32), 256, 0, stream>>>(XB, Wqa,  (float*)R2, 4096, 1536, 2048, 1.0f);
  gemm_bt<0><<<dim3( 8, 32), 256, 0, stream>>>(XB, Wkva, (float*)R3, 4096, 1024, 2048, 1.0f);
  rmsnorm_kernel<<<4096, 256, 0, stream>>>((const float*)R2, q_a_ln, Qlat, 1536);
  kv_split_kernel<<<4096, 256, 0, stream>>>((const float*)R3, kv_a_ln, cosT, sinT, KVlat, Kf);
  gemm_bt<1><<<dim3(24, 32), 256, 0, stream>>>(Qlat, Wqb, (u16*)R2, 4096, 3072, 1536, qscale);
  q_rope_kernel<<<8192, 256, 0, stream>>>((u16*)R2, cosT, sinT);
  gemm_bt<1><<<dim3(16, 32), 256, 0, stream>>>(KVlat, Wkvb, (u16*)R3, 4096, 2048, 512, 1.0f);
  knope_kernel<<<2048, 256, 0, stream>>>((const u16*)R3, Kf);
  v_transpose<<<512, 256, 0, stream>>>((const u16*)R3, Vt);
  attn_kernel<<<1024, 256, 0, stream>>>((const u16*)R2, Kf, Vt, XB);
  gemm_bt<0><<<dim3(16, 32), 256, 0, stream>>>(XB, Wo, (float*)d_out, 4096, 2048, 2048, 1.0f);
}

// Round 6
// 461.955 us; speedup vs baseline: 1.3644x; 1.3644x over previous
//
#include <hip/hip_runtime.h>

using u16 = unsigned short;
using u32 = unsigned int;

typedef float f32x4 __attribute__((ext_vector_type(4)));
typedef __bf16 bf16x8 __attribute__((ext_vector_type(8)));
typedef u16 u16x8 __attribute__((ext_vector_type(8)));

// ---------- helpers ----------
__device__ __forceinline__ u16 f2bf(float f){
  u32 u = __builtin_bit_cast(u32, f);
  u32 r = (u + 0x7fffu + ((u >> 16) & 1u)) >> 16;   // RNE
  return (u16)r;
}
__device__ __forceinline__ float bf2f(u16 h){
  u32 u = ((u32)h) << 16;
  return __builtin_bit_cast(float, u);
}
__device__ __forceinline__ void gl2lds16(const void* g, void* l){
  __builtin_amdgcn_global_load_lds((const __attribute__((address_space(1))) u32*)g,
                                   (__attribute__((address_space(3))) u32*)l, 16, 0, 0);
}
// 16B-chunk XOR swizzle within a row of 24 chunks (K rows, 192 elems)
__device__ __forceinline__ int swz24(int ck, int r){ return (ck & 24) | ((ck ^ r) & 7); }

// ---------- elementwise convert x ----------
__global__ __launch_bounds__(256) void cvt_f32_bf16(const float* __restrict__ in,
                                                    u16* __restrict__ out, long n){
  long i = ((long)blockIdx.x*256 + threadIdx.x)*4;
  if (i >= n) return;
  float4 v = *(const float4*)(in + i);
  u16 o[4] = { f2bf(v.x), f2bf(v.y), f2bf(v.z), f2bf(v.w) };
  *(ushort4*)(out + i) = *(ushort4*)o;
}

// ---------- weight transpose+convert: in fp32 [K][N] -> out bf16 [N][K] ----------
__global__ __launch_bounds__(256) void transpose_w(const float* __restrict__ in,
                                                   u16* __restrict__ out, int K, int N){
  __shared__ float tile[32][33];
  int n0 = blockIdx.x*32, k0 = blockIdx.y*32;
  int tx = threadIdx.x, ty = threadIdx.y;
  for (int i = ty; i < 32; i += 8)
    tile[i][tx] = in[(size_t)(k0+i)*N + n0+tx];
  __syncthreads();
  for (int i = ty; i < 32; i += 8)
    out[(size_t)(n0+i)*K + k0+tx] = f2bf(tile[tx][i]);
}

// ---------- rope tables (f64 trig) ----------
__global__ __launch_bounds__(256) void rope_tables(float* __restrict__ cosT, float* __restrict__ sinT){
  int idx = blockIdx.x*256 + threadIdx.x;   // 2048*32
  int t = idx >> 5, d = idx & 31;
  double inv = pow(10000.0, -(double)d / 32.0);
  double a = (double)t * inv;
  cosT[idx] = (float)cos(a);
  sinT[idx] = (float)sin(a);
}

// ---------- m97-style 128x128 bf16 MFMA GEMM, C = A[M][K] * Bt[N][K]^T ----------
template<int OUT_BF16>
__global__ __launch_bounds__(256) void gemm_bt(const u16* __restrict__ A,
                                               const u16* __restrict__ Bt,
                                               void* __restrict__ Cout,
                                               int M, int N, int K, float cscale){
  __shared__ u16 As[128*32];
  __shared__ u16 Bs[128*32];
  const int tid = threadIdx.x, lane = tid & 63, wave = tid >> 6;
  const int m0 = blockIdx.y*128, n0 = blockIdx.x*128;
  const int wm = (wave >> 1)*64, wn = (wave & 1)*64;
  const int g = lane >> 4, lr = lane & 15;
  f32x4 acc[4][4] = {};
  const int sr = (wave*2)*16 + (lane >> 2);      // staging row base for chunk i=0
  const int sc = (lane & 3)*8;                   // staging col
  for (int k0 = 0; k0 < K; k0 += 32){
    __syncthreads();
    #pragma unroll
    for (int i = 0; i < 2; i++){
      int c = wave*2 + i;
      int r = sr + i*16;
      gl2lds16(A  + (size_t)(m0+r)*K + k0 + sc, (char*)As + c*1024);
      gl2lds16(Bt + (size_t)(n0+r)*K + k0 + sc, (char*)Bs + c*1024);
    }
    __syncthreads();
    bf16x8 af[4], bfr[4];
    #pragma unroll
    for (int mi = 0; mi < 4; mi++) af[mi]  = *reinterpret_cast<const bf16x8*>(&As[(wm+mi*16+lr)*32 + g*8]);
    #pragma unroll
    for (int ni = 0; ni < 4; ni++) bfr[ni] = *reinterpret_cast<const bf16x8*>(&Bs[(wn+ni*16+lr)*32 + g*8]);
    #pragma unroll
    for (int mi = 0; mi < 4; mi++)
      #pragma unroll
      for (int ni = 0; ni < 4; ni++)
        acc[mi][ni] = __builtin_amdgcn_mfma_f32_16x16x32_bf16(af[mi], bfr[ni], acc[mi][ni], 0,0,0);
  }
  #pragma unroll
  for (int mi = 0; mi < 4; mi++)
    #pragma unroll
    for (int ni = 0; ni < 4; ni++)
      #pragma unroll
      for (int r = 0; r < 4; r++){
        int row = m0 + wm + mi*16 + g*4 + r;
        int col = n0 + wn + ni*16 + lr;
        float v = acc[mi][ni][r];
        if (OUT_BF16) ((u16*)Cout)[(size_t)row*N + col] = f2bf(v*cscale);
        else          ((float*)Cout)[(size_t)row*N + col] = v;
      }
}

// ---------- rmsnorm rows (fp32 in -> bf16 out) ----------
__global__ __launch_bounds__(256) void rmsnorm_kernel(const float* __restrict__ in,
                                                      const float* __restrict__ w,
                                                      u16* __restrict__ out, int ncols){
  int row = blockIdx.x;
  const float* x = in + (size_t)row*ncols;
  float ss = 0.f;
  for (int c = threadIdx.x; c < ncols; c += 256){ float v = x[c]; ss += v*v; }
  #pragma unroll
  for (int m = 1; m < 64; m <<= 1) ss += __shfl_xor(ss, m, 64);
  __shared__ float p[4];
  if ((threadIdx.x & 63) == 0) p[threadIdx.x >> 6] = ss;
  __syncthreads();
  float inv = rsqrtf((p[0]+p[1]+p[2]+p[3]) / (float)ncols + 1e-6f);
  u16* o = out + (size_t)row*ncols;
  for (int c = threadIdx.x; c < ncols; c += 256) o[c] = f2bf(x[c]*inv*w[c]);
}

// ---------- kv split: rmsnorm(first 512) -> kvlat ; rope(last 512) -> Kf rope cols ----------
__global__ __launch_bounds__(256) void kv_split_kernel(const float* __restrict__ kvraw,
                                                       const float* __restrict__ lnw,
                                                       const float* __restrict__ cosT,
                                                       const float* __restrict__ sinT,
                                                       u16* __restrict__ kvlat,
                                                       u16* __restrict__ Kf){
  int row = blockIdx.x;                       // 0..4095
  int t = row & 2047, b = row >> 11;
  const float* x = kvraw + (size_t)row*1024;
  float ss = 0.f;
  for (int c = threadIdx.x; c < 512; c += 256){ float v = x[c]; ss += v*v; }
  #pragma unroll
  for (int m = 1; m < 64; m <<= 1) ss += __shfl_xor(ss, m, 64);
  __shared__ float p[4];
  if ((threadIdx.x & 63) == 0) p[threadIdx.x >> 6] = ss;
  __syncthreads();
  float inv = rsqrtf((p[0]+p[1]+p[2]+p[3]) / 512.0f + 1e-6f);
  for (int c = threadIdx.x; c < 512; c += 256)
    kvlat[(size_t)row*512 + c] = f2bf(x[c]*inv*lnw[c]);
  // rope: 8 heads x 32 pairs = 256 threads exactly
  int kh = threadIdx.x >> 5, dp = threadIdx.x & 31;
  float x1 = x[512 + kh*64 + dp], x2 = x[512 + kh*64 + dp + 32];
  float cv = cosT[t*32 + dp], sv = sinT[t*32 + dp];
  float o1 = x1*cv - x2*sv;
  float o2 = x2*cv + x1*sv;
  u16* kr = Kf + ((size_t)(b*8 + kh)*2048 + t)*192;
  int c1 = 128 + dp, c2 = 128 + dp + 32;
  kr[(swz24(c1 >> 3, t) << 3) | (c1 & 7)] = f2bf(o1);
  kr[(swz24(c2 >> 3, t) << 3) | (c2 & 7)] = f2bf(o2);
}

// ---------- q rope in place on q bf16 [4096][3072] ----------
__global__ __launch_bounds__(256) void q_rope_kernel(u16* __restrict__ q,
                                                     const float* __restrict__ cosT,
                                                     const float* __restrict__ sinT){
  int idx = blockIdx.x*256 + threadIdx.x;     // 4096*16*32
  int row = idx >> 9, rem = idx & 511;
  int h = rem >> 5, dp = rem & 31;
  int t = row & 2047;
  u16* pq = q + (size_t)row*3072 + h*192 + 128;
  float x1 = bf2f(pq[dp]), x2 = bf2f(pq[dp+32]);
  float cv = cosT[t*32 + dp], sv = sinT[t*32 + dp];
  pq[dp]    = f2bf(x1*cv - x2*sv);
  pq[dp+32] = f2bf(x2*cv + x1*sv);
}

// ---------- k_nope copy (16B chunks, swizzled) ----------
__global__ __launch_bounds__(256) void knope_kernel(const u16* __restrict__ kv,
                                                    u16* __restrict__ Kf){
  int idx = blockIdx.x*256 + threadIdx.x;     // 4096*8*16
  int row = idx >> 7, rem = idx & 127;
  int kh = rem >> 4, ck = rem & 15;
  int t = row & 2047, b = row >> 11;
  int ck2 = (ck & 8) | ((ck ^ t) & 7);
  uint4 v = *(const uint4*)(kv + (size_t)row*2048 + kh*256 + ck*8);
  *(uint4*)(Kf + ((size_t)(b*8 + kh)*2048 + t)*192 + ck2*8) = v;
}

// ---------- V transpose: kv[row][kvh*256+128+vd] -> vT[b][kvh][vd][t] (t-chunks swizzled) ----------
__global__ __launch_bounds__(256) void v_transpose(const u16* __restrict__ kv,
                                                   u16* __restrict__ vT){
  int bid = blockIdx.x;                        // 2*8*32
  int tt = bid & 31, kvh = (bid >> 5) & 7, b = bid >> 8;
  int t0 = tt*64;
  __shared__ u16 tile[64][136];
  int tid = threadIdx.x;
  #pragma unroll
  for (int i = 0; i < 4; i++){
    int c = tid + i*256;                       // 1024 chunks of 8 elems
    int r = c >> 4, ck = c & 15;
    const u16* src = kv + ((size_t)(b*2048 + t0 + r))*2048 + kvh*256 + 128 + ck*8;
    *(uint4*)&tile[r][ck*8] = *(const uint4*)src;
  }
  __syncthreads();
  #pragma unroll
  for (int i = 0; i < 4; i++){
    int c = tid + i*256;                       // 128 vd * 8 t-chunks
    int vd = c >> 3, tc = c & 7;
    int stc = tc ^ (vd & 7);
    uint4 tv;
    u16* tp = (u16*)&tv;
    #pragma unroll
    for (int j = 0; j < 8; j++) tp[j] = tile[tc*8 + j][vd];
    *(uint4*)(vT + ((size_t)(b*8 + kvh)*128 + vd)*2048 + t0 + stc*8) = tv;
  }
}

// ---------- flash attention: XCD-grouped, single-K + single-V LDS pipeline, 48KB LDS ----------
// Q is PRE-SCALED by 192^-0.5 (folded into q_b gemm epilogue).
__global__ __launch_bounds__(256, 3) void attn_kernel(const u16* __restrict__ Q,
                                                      const u16* __restrict__ Kf,
                                                      const u16* __restrict__ Vt,
                                                      u16* __restrict__ Oa){
  constexpr int T = 2048;
  constexpr int NT = T/64;
  __shared__ u16 Ks[64*192];       // 24KB single buffer
  __shared__ u16 Vs[128*64];       // 16KB single buffer
  __shared__ u16 Ps[4][1024];      // 8KB
  const int tid = threadIdx.x, lane = tid & 63, wave = tid >> 6;
  const int g = lane >> 4, lr = lane & 15;

  // bijective XCD swizzle: all 64 blocks of one (b,kvh) group land on one XCD
  const int wg = blockIdx.x;                 // 0..1023
  const int role = (wg & 7)*128 + (wg >> 3); // xcd*128 + slot
  const int grp = role >> 6;                 // b*8 + kvh
  const int b = grp >> 3, kvh = grp & 7;
  const int within = role & 63;
  const int h = kvh*2 + (within >> 5);
  const int q0 = (within & 31)*64 + wave*16;

  bf16x8 aq[6];
  {
    const u16* qrow = Q + ((size_t)b*T + q0 + lr)*3072 + h*192;
    #pragma unroll
    for (int kc = 0; kc < 6; kc++)
      aq[kc] = *reinterpret_cast<const bf16x8*>(qrow + kc*32 + g*8);
  }
  const u16* Kbase = Kf + (size_t)(b*8 + kvh)*T*192;
  const u16* Vbase = Vt + (size_t)(b*8 + kvh)*128*T;

  // ones B-fragment (col 0 of B = 1.0) for row-sum-via-MFMA
  u16x8 onesb_u = {};
  #pragma unroll
  for (int j = 0; j < 8; j++) onesb_u[j] = (lr == 0) ? (u16)0x3F80 : (u16)0;
  const bf16x8 ones_b = __builtin_bit_cast(bf16x8, onesb_u);

  f32x4 ovb[8] = {};
  float mrow[4] = {-1e30f,-1e30f,-1e30f,-1e30f};
  float lp[4] = {};              // row-sum partials, MFMA-D layout (valid at lr==0)

  auto stageK = [&](int kt){
    const u16* ksrc = Kbase + (size_t)kt*12288 + wave*3072 + lane*8;
    #pragma unroll
    for (int i = 0; i < 6; i++)
      gl2lds16(ksrc + i*512, (char*)Ks + (wave*6 + i)*1024);
  };
  auto stageV = [&](int kt){
    #pragma unroll
    for (int i = 0; i < 4; i++){
      int c = wave*4 + i;
      const u16* vsrc = Vbase + (size_t)(c*8 + (lane >> 3))*T + kt*64 + (lane & 7)*8;
      gl2lds16(vsrc, (char*)Vs + c*1024);
    }
  };

  stageK(0);
  stageV(0);
  __syncthreads();               // vmcnt(0) drain: K & V tile 0 ready

  for (int kt = 0; kt < NT; kt++){
    const bool notlast = (kt + 1 < NT);

    // ---- QK^T (Q pre-scaled) ----
    f32x4 s[4];
    __builtin_amdgcn_s_setprio(1);
    #pragma unroll
    for (int nb = 0; nb < 4; nb++){
      const int row = nb*16 + lr;
      f32x4 a = {0.f,0.f,0.f,0.f};
      #pragma unroll
      for (int kc = 0; kc < 6; kc++){
        int ckl = swz24(kc*4 + g, row);
        bf16x8 kf = *reinterpret_cast<const bf16x8*>(&Ks[row*192 + ckl*8]);
        a = __builtin_amdgcn_mfma_f32_16x16x32_bf16(aq[kc], kf, a, 0,0,0);
      }
      s[nb] = a;
    }
    __builtin_amdgcn_s_setprio(0);

    // barrier_A: all waves done reading Ks; drains V(kt) staging (issued ~1 phase ago)
    __syncthreads();
    if (notlast) stageK(kt + 1);   // DMA next K into same buffer; hidden under softmax+PV

    // ---- softmax: defer-max THR=8 ----
    float tmax[4];
    #pragma unroll
    for (int r = 0; r < 4; r++){
      float v = fmaxf(fmaxf(s[0][r], s[1][r]), fmaxf(s[2][r], s[3][r]));
      v = fmaxf(v, __shfl_xor(v, 1, 64));
      v = fmaxf(v, __shfl_xor(v, 2, 64));
      v = fmaxf(v, __shfl_xor(v, 4, 64));
      v = fmaxf(v, __shfl_xor(v, 8, 64));
      tmax[r] = v;
    }
    int ok = (tmax[0] <= mrow[0] + 8.f) & (tmax[1] <= mrow[1] + 8.f) &
             (tmax[2] <= mrow[2] + 8.f) & (tmax[3] <= mrow[3] + 8.f);
    if (!__all(ok)){
      #pragma unroll
      for (int r = 0; r < 4; r++){
        float mn = fmaxf(mrow[r], tmax[r]);
        float corr = __expf(mrow[r] - mn);
        mrow[r] = mn;
        lp[r] *= corr;
        #pragma unroll
        for (int vb = 0; vb < 8; vb++) ovb[vb][r] *= corr;
      }
    }
    #pragma unroll
    for (int nb = 0; nb < 4; nb++)
      #pragma unroll
      for (int r = 0; r < 4; r++){
        float pv = __expf(s[nb][r] - mrow[r]);
        int prow = g*4 + r, col = nb*16 + lr;
        int ck = (col >> 3) ^ (prow & 7);
        Ps[wave][prow*64 + ck*8 + (col & 7)] = f2bf(pv);
      }

    // wave-local LDS write->read fence (Ps is per-wave private)
    asm volatile("s_waitcnt lgkmcnt(0)" ::: "memory");
    __builtin_amdgcn_sched_barrier(0);

    // ---- PV: P from LDS, V from Vs; row-sum via ones-MFMA ----
    bf16x8 ap[2];
    #pragma unroll
    for (int k2 = 0; k2 < 2; k2++){
      int ck = (k2*4 + g) ^ (lr & 7);
      ap[k2] = *reinterpret_cast<const bf16x8*>(&Ps[wave][lr*64 + ck*8]);
    }
    {
      f32x4 ts = {0.f,0.f,0.f,0.f};
      ts = __builtin_amdgcn_mfma_f32_16x16x32_bf16(ap[0], ones_b, ts, 0,0,0);
      ts = __builtin_amdgcn_mfma_f32_16x16x32_bf16(ap[1], ones_b, ts, 0,0,0);
      #pragma unroll
      for (int r = 0; r < 4; r++) lp[r] += ts[r];
    }
    __builtin_amdgcn_s_setprio(1);
    #pragma unroll
    for (int vb = 0; vb < 8; vb++)
      #pragma unroll
      for (int k2 = 0; k2 < 2; k2++){
        int vd = vb*16 + lr;
        int ck = (k2*4 + g) ^ (vd & 7);
        bf16x8 bv = *reinterpret_cast<const bf16x8*>(&Vs[vd*64 + ck*8]);
        ovb[vb] = __builtin_amdgcn_mfma_f32_16x16x32_bf16(ap[k2], bv, ovb[vb], 0,0,0);
      }
    __builtin_amdgcn_s_setprio(0);

    if (notlast){
      __syncthreads();           // barrier_B: drains K(kt+1); all waves done reading Vs(kt)
      stageV(kt + 1);            // DMA next V; hidden under next QK^T, drained at next barrier_A
    }
  }

  // ---- epilogue: broadcast row-sums from lr==0 lanes, normalize, store ----
  float inv[4];
  #pragma unroll
  for (int r = 0; r < 4; r++){
    float sum = __shfl(lp[r], lane & 48, 64);
    inv[r] = 1.0f / sum;
  }
  u16* obase = Oa + ((size_t)b*T + q0)*2048 + h*128;
  #pragma unroll
  for (int vb = 0; vb < 8; vb++)
    #pragma unroll
    for (int r = 0; r < 4; r++)
      obase[(size_t)(g*4 + r)*2048 + vb*16 + lr] = f2bf(ovb[vb][r]*inv[r]);
}

// ---------- launch ----------
extern "C" void kernel_launch(void* const* d_in, const int* in_sizes, int n_in,
                              void* d_out, int out_size, void* d_ws, size_t ws_size,
                              hipStream_t stream){
  const float* hs      = (const float*)d_in[0];
  const float* q_a_w   = (const float*)d_in[1];
  const float* q_a_ln  = (const float*)d_in[2];
  const float* q_b_w   = (const float*)d_in[3];
  const float* kv_a_w  = (const float*)d_in[4];
  const float* kv_a_ln = (const float*)d_in[5];
  const float* kv_b_w  = (const float*)d_in[6];
  const float* o_w     = (const float*)d_in[7];

  char* ws = (char*)d_ws;
  size_t off = 0;
  auto alloc = [&](size_t bytes){ void* p = ws + off; off += bytes; return p; };
  u16*  Wqa   = (u16*)alloc(1536ull*2048*2);
  u16*  Wqb   = (u16*)alloc(3072ull*1536*2);
  u16*  Wkva  = (u16*)alloc(1024ull*2048*2);
  u16*  Wkvb  = (u16*)alloc(2048ull*512*2);
  u16*  Wo    = (u16*)alloc(2048ull*2048*2);
  u16*  XB    = (u16*)alloc(4096ull*2048*2);      // x bf16 -> later attn output
  char* R2    = (char*)alloc(4096ull*1536*4);     // q_a fp32 -> later q bf16 [4096][3072]
  char* R3    = (char*)alloc(4096ull*1024*4);     // kv_raw fp32 -> later kv bf16 [4096][2048]
  u16*  Qlat  = (u16*)alloc(4096ull*1536*2);
  u16*  KVlat = (u16*)alloc(4096ull*512*2);
  u16*  Kf    = (u16*)alloc(2ull*8*2048*192*2);
  u16*  Vt    = (u16*)alloc(2ull*8*128*2048*2);
  float* cosT = (float*)alloc(2048ull*32*4);
  float* sinT = (float*)alloc(2048ull*32*4);
  (void)ws_size; (void)in_sizes; (void)n_in; (void)out_size;

  const float qscale = 0.07216878364870322f;      // 192^-0.5 folded into q_b gemm

  cvt_f32_bf16<<<8192, 256, 0, stream>>>(hs, XB, 4096ll*2048);
  transpose_w<<<dim3(1536/32, 2048/32), dim3(32,8), 0, stream>>>(q_a_w,  Wqa,  2048, 1536);
  transpose_w<<<dim3(3072/32, 1536/32), dim3(32,8), 0, stream>>>(q_b_w,  Wqb,  1536, 3072);
  transpose_w<<<dim3(1024/32, 2048/32), dim3(32,8), 0, stream>>>(kv_a_w, Wkva, 2048, 1024);
  transpose_w<<<dim3(2048/32,  512/32), dim3(32,8), 0, stream>>>(kv_b_w, Wkvb,  512, 2048);
  transpose_w<<<dim3(2048/32, 2048/32), dim3(32,8), 0, stream>>>(o_w,    Wo,   2048, 2048);
  rope_tables<<<256, 256, 0, stream>>>(cosT, sinT);

  gemm_bt<0><<<dim3(12, 32), 256, 0, stream>>>(XB, Wqa,  (float*)R2, 4096, 1536, 2048, 1.0f);
  gemm_bt<0><<<dim3( 8, 32), 256, 0, stream>>>(XB, Wkva, (float*)R3, 4096, 1024, 2048, 1.0f);
  rmsnorm_kernel<<<4096, 256, 0, stream>>>((const float*)R2, q_a_ln, Qlat, 1536);
  kv_split_kernel<<<4096, 256, 0, stream>>>((const float*)R3, kv_a_ln, cosT, sinT, KVlat, Kf);
  gemm_bt<1><<<dim3(24, 32), 256, 0, stream>>>(Qlat, Wqb, (u16*)R2, 4096, 3072, 1536, qscale);
  q_rope_kernel<<<8192, 256, 0, stream>>>((u16*)R2, cosT, sinT);
  gemm_bt<1><<<dim3(16, 32), 256, 0, stream>>>(KVlat, Wkvb, (u16*)R3, 4096, 2048, 512, 1.0f);
  knope_kernel<<<2048, 256, 0, stream>>>((const u16*)R3, Kf);
  v_transpose<<<512, 256, 0, stream>>>((const u16*)R3, Vt);
  attn_kernel<<<1024, 256, 0, stream>>>((const u16*)R2, Kf, Vt, XB);
  gemm_bt<0><<<dim3(16, 32), 256, 0, stream>>>(XB, Wo, (float*)d_out, 4096, 2048, 2048, 1.0f);
}

// Round 7
// 423.848 us; speedup vs baseline: 1.4870x; 1.0899x over previous
//
#include <hip/hip_runtime.h>

using u16 = unsigned short;
using u32 = unsigned int;

typedef float f32x4 __attribute__((ext_vector_type(4)));
typedef __bf16 bf16x8 __attribute__((ext_vector_type(8)));
typedef u16 u16x8 __attribute__((ext_vector_type(8)));

// ---------- helpers ----------
__device__ __forceinline__ u16 f2bf(float f){
  u32 u = __builtin_bit_cast(u32, f);
  u32 r = (u + 0x7fffu + ((u >> 16) & 1u)) >> 16;   // RNE
  return (u16)r;
}
__device__ __forceinline__ float bf2f(u16 h){
  u32 u = ((u32)h) << 16;
  return __builtin_bit_cast(float, u);
}
__device__ __forceinline__ void gl2lds16(const void* g, void* l){
  __builtin_amdgcn_global_load_lds((const __attribute__((address_space(1))) u32*)g,
                                   (__attribute__((address_space(3))) u32*)l, 16, 0, 0);
}
// 16B-chunk XOR swizzle within a row of 24 chunks (K rows, 192 elems)
__device__ __forceinline__ int swz24(int ck, int r){ return (ck & 24) | ((ck ^ r) & 7); }

// ---------- elementwise convert x ----------
__global__ __launch_bounds__(256) void cvt_f32_bf16(const float* __restrict__ in,
                                                    u16* __restrict__ out, long n){
  long i = ((long)blockIdx.x*256 + threadIdx.x)*4;
  if (i >= n) return;
  float4 v = *(const float4*)(in + i);
  u16 o[4] = { f2bf(v.x), f2bf(v.y), f2bf(v.z), f2bf(v.w) };
  *(ushort4*)(out + i) = *(ushort4*)o;
}

// ---------- weight transpose+convert: in fp32 [K][N] -> out bf16 [N][K] ----------
__global__ __launch_bounds__(256) void transpose_w(const float* __restrict__ in,
                                                   u16* __restrict__ out, int K, int N){
  __shared__ float tile[32][33];
  int n0 = blockIdx.x*32, k0 = blockIdx.y*32;
  int tx = threadIdx.x, ty = threadIdx.y;
  for (int i = ty; i < 32; i += 8)
    tile[i][tx] = in[(size_t)(k0+i)*N + n0+tx];
  __syncthreads();
  for (int i = ty; i < 32; i += 8)
    out[(size_t)(n0+i)*K + k0+tx] = f2bf(tile[tx][i]);
}

// ---------- rope tables (f64 trig) ----------
__global__ __launch_bounds__(256) void rope_tables(float* __restrict__ cosT, float* __restrict__ sinT){
  int idx = blockIdx.x*256 + threadIdx.x;   // 2048*32
  int t = idx >> 5, d = idx & 31;
  double inv = pow(10000.0, -(double)d / 32.0);
  double a = (double)t * inv;
  cosT[idx] = (float)cos(a);
  sinT[idx] = (float)sin(a);
}

// ---------- m97-style 128x128 bf16 MFMA GEMM, C = A[M][K] * Bt[N][K]^T ----------
template<int OUT_BF16>
__global__ __launch_bounds__(256) void gemm_bt(const u16* __restrict__ A,
                                               const u16* __restrict__ Bt,
                                               void* __restrict__ Cout,
                                               int M, int N, int K, float cscale){
  __shared__ u16 As[128*32];
  __shared__ u16 Bs[128*32];
  const int tid = threadIdx.x, lane = tid & 63, wave = tid >> 6;
  const int m0 = blockIdx.y*128, n0 = blockIdx.x*128;
  const int wm = (wave >> 1)*64, wn = (wave & 1)*64;
  const int g = lane >> 4, lr = lane & 15;
  f32x4 acc[4][4] = {};
  const int sr = (wave*2)*16 + (lane >> 2);      // staging row base for chunk i=0
  const int sc = (lane & 3)*8;                   // staging col
  for (int k0 = 0; k0 < K; k0 += 32){
    __syncthreads();
    #pragma unroll
    for (int i = 0; i < 2; i++){
      int c = wave*2 + i;
      int r = sr + i*16;
      gl2lds16(A  + (size_t)(m0+r)*K + k0 + sc, (char*)As + c*1024);
      gl2lds16(Bt + (size_t)(n0+r)*K + k0 + sc, (char*)Bs + c*1024);
    }
    __syncthreads();
    bf16x8 af[4], bfr[4];
    #pragma unroll
    for (int mi = 0; mi < 4; mi++) af[mi]  = *reinterpret_cast<const bf16x8*>(&As[(wm+mi*16+lr)*32 + g*8]);
    #pragma unroll
    for (int ni = 0; ni < 4; ni++) bfr[ni] = *reinterpret_cast<const bf16x8*>(&Bs[(wn+ni*16+lr)*32 + g*8]);
    #pragma unroll
    for (int mi = 0; mi < 4; mi++)
      #pragma unroll
      for (int ni = 0; ni < 4; ni++)
        acc[mi][ni] = __builtin_amdgcn_mfma_f32_16x16x32_bf16(af[mi], bfr[ni], acc[mi][ni], 0,0,0);
  }
  #pragma unroll
  for (int mi = 0; mi < 4; mi++)
    #pragma unroll
    for (int ni = 0; ni < 4; ni++)
      #pragma unroll
      for (int r = 0; r < 4; r++){
        int row = m0 + wm + mi*16 + g*4 + r;
        int col = n0 + wn + ni*16 + lr;
        float v = acc[mi][ni][r];
        if (OUT_BF16) ((u16*)Cout)[(size_t)row*N + col] = f2bf(v*cscale);
        else          ((float*)Cout)[(size_t)row*N + col] = v;
      }
}

// ---------- rmsnorm rows (fp32 in -> bf16 out) ----------
__global__ __launch_bounds__(256) void rmsnorm_kernel(const float* __restrict__ in,
                                                      const float* __restrict__ w,
                                                      u16* __restrict__ out, int ncols){
  int row = blockIdx.x;
  const float* x = in + (size_t)row*ncols;
  float ss = 0.f;
  for (int c = threadIdx.x; c < ncols; c += 256){ float v = x[c]; ss += v*v; }
  #pragma unroll
  for (int m = 1; m < 64; m <<= 1) ss += __shfl_xor(ss, m, 64);
  __shared__ float p[4];
  if ((threadIdx.x & 63) == 0) p[threadIdx.x >> 6] = ss;
  __syncthreads();
  float inv = rsqrtf((p[0]+p[1]+p[2]+p[3]) / (float)ncols + 1e-6f);
  u16* o = out + (size_t)row*ncols;
  for (int c = threadIdx.x; c < ncols; c += 256) o[c] = f2bf(x[c]*inv*w[c]);
}

// ---------- kv split: rmsnorm(first 512) -> kvlat ; rope(last 512) -> Kf rope cols ----------
__global__ __launch_bounds__(256) void kv_split_kernel(const float* __restrict__ kvraw,
                                                       const float* __restrict__ lnw,
                                                       const float* __restrict__ cosT,
                                                       const float* __restrict__ sinT,
                                                       u16* __restrict__ kvlat,
                                                       u16* __restrict__ Kf){
  int row = blockIdx.x;                       // 0..4095
  int t = row & 2047, b = row >> 11;
  const float* x = kvraw + (size_t)row*1024;
  float ss = 0.f;
  for (int c = threadIdx.x; c < 512; c += 256){ float v = x[c]; ss += v*v; }
  #pragma unroll
  for (int m = 1; m < 64; m <<= 1) ss += __shfl_xor(ss, m, 64);
  __shared__ float p[4];
  if ((threadIdx.x & 63) == 0) p[threadIdx.x >> 6] = ss;
  __syncthreads();
  float inv = rsqrtf((p[0]+p[1]+p[2]+p[3]) / 512.0f + 1e-6f);
  for (int c = threadIdx.x; c < 512; c += 256)
    kvlat[(size_t)row*512 + c] = f2bf(x[c]*inv*lnw[c]);
  // rope: 8 heads x 32 pairs = 256 threads exactly
  int kh = threadIdx.x >> 5, dp = threadIdx.x & 31;
  float x1 = x[512 + kh*64 + dp], x2 = x[512 + kh*64 + dp + 32];
  float cv = cosT[t*32 + dp], sv = sinT[t*32 + dp];
  float o1 = x1*cv - x2*sv;
  float o2 = x2*cv + x1*sv;
  u16* kr = Kf + ((size_t)(b*8 + kh)*2048 + t)*192;
  int c1 = 128 + dp, c2 = 128 + dp + 32;
  kr[(swz24(c1 >> 3, t) << 3) | (c1 & 7)] = f2bf(o1);
  kr[(swz24(c2 >> 3, t) << 3) | (c2 & 7)] = f2bf(o2);
}

// ---------- q rope in place on q bf16 [4096][3072] ----------
__global__ __launch_bounds__(256) void q_rope_kernel(u16* __restrict__ q,
                                                     const float* __restrict__ cosT,
                                                     const float* __restrict__ sinT){
  int idx = blockIdx.x*256 + threadIdx.x;     // 4096*16*32
  int row = idx >> 9, rem = idx & 511;
  int h = rem >> 5, dp = rem & 31;
  int t = row & 2047;
  u16* pq = q + (size_t)row*3072 + h*192 + 128;
  float x1 = bf2f(pq[dp]), x2 = bf2f(pq[dp+32]);
  float cv = cosT[t*32 + dp], sv = sinT[t*32 + dp];
  pq[dp]    = f2bf(x1*cv - x2*sv);
  pq[dp+32] = f2bf(x2*cv + x1*sv);
}

// ---------- k_nope copy (16B chunks, swizzled) ----------
__global__ __launch_bounds__(256) void knope_kernel(const u16* __restrict__ kv,
                                                    u16* __restrict__ Kf){
  int idx = blockIdx.x*256 + threadIdx.x;     // 4096*8*16
  int row = idx >> 7, rem = idx & 127;
  int kh = rem >> 4, ck = rem & 15;
  int t = row & 2047, b = row >> 11;
  int ck2 = (ck & 8) | ((ck ^ t) & 7);
  uint4 v = *(const uint4*)(kv + (size_t)row*2048 + kh*256 + ck*8);
  *(uint4*)(Kf + ((size_t)(b*8 + kh)*2048 + t)*192 + ck2*8) = v;
}

// ---------- V transpose: kv[row][kvh*256+128+vd] -> vT[b][kvh][vd][t] (t-chunks swizzled) ----------
__global__ __launch_bounds__(256) void v_transpose(const u16* __restrict__ kv,
                                                   u16* __restrict__ vT){
  int bid = blockIdx.x;                        // 2*8*32
  int tt = bid & 31, kvh = (bid >> 5) & 7, b = bid >> 8;
  int t0 = tt*64;
  __shared__ u16 tile[64][136];
  int tid = threadIdx.x;
  #pragma unroll
  for (int i = 0; i < 4; i++){
    int c = tid + i*256;                       // 1024 chunks of 8 elems
    int r = c >> 4, ck = c & 15;
    const u16* src = kv + ((size_t)(b*2048 + t0 + r))*2048 + kvh*256 + 128 + ck*8;
    *(uint4*)&tile[r][ck*8] = *(const uint4*)src;
  }
  __syncthreads();
  #pragma unroll
  for (int i = 0; i < 4; i++){
    int c = tid + i*256;                       // 128 vd * 8 t-chunks
    int vd = c >> 3, tc = c & 7;
    int stc = tc ^ (vd & 7);
    uint4 tv;
    u16* tp = (u16*)&tv;
    #pragma unroll
    for (int j = 0; j < 8; j++) tp[j] = tile[tc*8 + j][vd];
    *(uint4*)(vT + ((size_t)(b*8 + kvh)*128 + vd)*2048 + t0 + stc*8) = tv;
  }
}

// ---------- flash attention: XCD-grouped, 2 q-groups/wave, single-K + double-V LDS pipeline ----------
// Q is PRE-SCALED by 192^-0.5 (folded into q_b gemm epilogue).
__global__ __launch_bounds__(256, 2) void attn_kernel(const u16* __restrict__ Q,
                                                      const u16* __restrict__ Kf,
                                                      const u16* __restrict__ Vt,
                                                      u16* __restrict__ Oa){
  constexpr int T = 2048;
  constexpr int NT = T/64;
  __shared__ u16 Ks[64*192];       // 24KB single buffer
  __shared__ u16 Vs[2][128*64];    // 32KB double buffer
  __shared__ u16 Ps[4][2048];      // 16KB: per wave, 2 qg x 16 rows x 64 cols
  const int tid = threadIdx.x, lane = tid & 63, wave = tid >> 6;
  const int g = lane >> 4, lr = lane & 15;

  // bijective XCD swizzle: all 32 blocks of one (b,kvh) group land on one XCD (2 groups/XCD)
  const int wg = blockIdx.x;                 // 0..511
  const int role = (wg & 7)*64 + (wg >> 3);  // xcd*64 + slot
  const int grp = role >> 5;                 // b*8 + kvh
  const int b = grp >> 3, kvh = grp & 7;
  const int within = role & 31;
  const int h = kvh*2 + (within >> 4);
  const int q0 = (within & 15)*128 + wave*32;

  bf16x8 aq[2][6];
  #pragma unroll
  for (int qg = 0; qg < 2; qg++){
    const u16* qrow = Q + ((size_t)b*T + q0 + qg*16 + lr)*3072 + h*192;
    #pragma unroll
    for (int kc = 0; kc < 6; kc++)
      aq[qg][kc] = *reinterpret_cast<const bf16x8*>(qrow + kc*32 + g*8);
  }
  const u16* Kbase = Kf + (size_t)(b*8 + kvh)*T*192;
  const u16* Vbase = Vt + (size_t)(b*8 + kvh)*128*T;

  // ones B-fragment (col 0 of B = 1.0) for row-sum-via-MFMA
  u16x8 onesb_u = {};
  #pragma unroll
  for (int j = 0; j < 8; j++) onesb_u[j] = (lr == 0) ? (u16)0x3F80 : (u16)0;
  const bf16x8 ones_b = __builtin_bit_cast(bf16x8, onesb_u);

  f32x4 ovb[2][8] = {};
  float mrow[2][4] = {{-1e30f,-1e30f,-1e30f,-1e30f},{-1e30f,-1e30f,-1e30f,-1e30f}};
  float lp[2][4] = {};           // row-sum partials, MFMA-D layout (valid at lr==0)

  auto stageK = [&](int kt){
    const u16* ksrc = Kbase + (size_t)kt*12288 + wave*3072 + lane*8;
    #pragma unroll
    for (int i = 0; i < 6; i++)
      gl2lds16(ksrc + i*512, (char*)Ks + (wave*6 + i)*1024);
  };
  auto stageV = [&](int kt, int buf){
    #pragma unroll
    for (int i = 0; i < 4; i++){
      int c = wave*4 + i;
      const u16* vsrc = Vbase + (size_t)(c*8 + (lane >> 3))*T + kt*64 + (lane & 7)*8;
      gl2lds16(vsrc, (char*)(&Vs[0][0]) + buf*16384 + c*1024);
    }
  };

  stageK(0);
  stageV(0, 0);
  __syncthreads();               // vmcnt(0) drain: K & V tile 0 ready

  int buf = 0;
  for (int kt = 0; kt < NT; kt++){
    const bool notlast = (kt + 1 < NT);

    // prefetch next V into other buffer; hidden under QK+softmax+PV
    if (notlast) stageV(kt + 1, buf ^ 1);

    // ---- QK^T (Q pre-scaled); K-frags shared across both q-groups ----
    f32x4 s[2][4];
    __builtin_amdgcn_s_setprio(1);
    #pragma unroll
    for (int nb = 0; nb < 4; nb++){
      const int row = nb*16 + lr;
      f32x4 a0 = {0.f,0.f,0.f,0.f}, a1 = {0.f,0.f,0.f,0.f};
      #pragma unroll
      for (int kc = 0; kc < 6; kc++){
        int ckl = swz24(kc*4 + g, row);
        bf16x8 kf = *reinterpret_cast<const bf16x8*>(&Ks[row*192 + ckl*8]);
        a0 = __builtin_amdgcn_mfma_f32_16x16x32_bf16(aq[0][kc], kf, a0, 0,0,0);
        a1 = __builtin_amdgcn_mfma_f32_16x16x32_bf16(aq[1][kc], kf, a1, 0,0,0);
      }
      s[0][nb] = a0; s[1][nb] = a1;
    }
    __builtin_amdgcn_s_setprio(0);

    // barrier_A: all waves done reading Ks. lgkm-only (V prefetch stays in flight).
    asm volatile("s_waitcnt lgkmcnt(0)" ::: "memory");
    __builtin_amdgcn_s_barrier();
    __builtin_amdgcn_sched_barrier(0);
    if (notlast) stageK(kt + 1);   // DMA next K into same buffer; hidden under softmax+PV

    // ---- softmax per q-group: defer-max THR=8 ----
    #pragma unroll
    for (int qg = 0; qg < 2; qg++){
      float tmax[4];
      #pragma unroll
      for (int r = 0; r < 4; r++){
        float v = fmaxf(fmaxf(s[qg][0][r], s[qg][1][r]), fmaxf(s[qg][2][r], s[qg][3][r]));
        v = fmaxf(v, __shfl_xor(v, 1, 64));
        v = fmaxf(v, __shfl_xor(v, 2, 64));
        v = fmaxf(v, __shfl_xor(v, 4, 64));
        v = fmaxf(v, __shfl_xor(v, 8, 64));
        tmax[r] = v;
      }
      int ok = (tmax[0] <= mrow[qg][0] + 8.f) & (tmax[1] <= mrow[qg][1] + 8.f) &
               (tmax[2] <= mrow[qg][2] + 8.f) & (tmax[3] <= mrow[qg][3] + 8.f);
      if (!__all(ok)){
        #pragma unroll
        for (int r = 0; r < 4; r++){
          float mn = fmaxf(mrow[qg][r], tmax[r]);
          float corr = __expf(mrow[qg][r] - mn);
          mrow[qg][r] = mn;
          lp[qg][r] *= corr;
          #pragma unroll
          for (int vb = 0; vb < 8; vb++) ovb[qg][vb][r] *= corr;
        }
      }
      #pragma unroll
      for (int nb = 0; nb < 4; nb++)
        #pragma unroll
        for (int r = 0; r < 4; r++){
          float pv = __expf(s[qg][nb][r] - mrow[qg][r]);
          int prow = g*4 + r, col = nb*16 + lr;
          int ck = (col >> 3) ^ (prow & 7);
          Ps[wave][qg*1024 + prow*64 + ck*8 + (col & 7)] = f2bf(pv);
        }
    }

    // wave-local LDS write->read fence (Ps is per-wave private)
    asm volatile("s_waitcnt lgkmcnt(0)" ::: "memory");
    __builtin_amdgcn_sched_barrier(0);

    // ---- PV: P from LDS, V from Vs[buf]; V-frags shared across q-groups ----
    bf16x8 ap[2][2];
    #pragma unroll
    for (int qg = 0; qg < 2; qg++)
      #pragma unroll
      for (int k2 = 0; k2 < 2; k2++){
        int ck = (k2*4 + g) ^ (lr & 7);
        ap[qg][k2] = *reinterpret_cast<const bf16x8*>(&Ps[wave][qg*1024 + lr*64 + ck*8]);
      }
    #pragma unroll
    for (int qg = 0; qg < 2; qg++){
      f32x4 ts = {0.f,0.f,0.f,0.f};
      ts = __builtin_amdgcn_mfma_f32_16x16x32_bf16(ap[qg][0], ones_b, ts, 0,0,0);
      ts = __builtin_amdgcn_mfma_f32_16x16x32_bf16(ap[qg][1], ones_b, ts, 0,0,0);
      #pragma unroll
      for (int r = 0; r < 4; r++) lp[qg][r] += ts[r];
    }
    __builtin_amdgcn_s_setprio(1);
    #pragma unroll
    for (int vb = 0; vb < 8; vb++)
      #pragma unroll
      for (int k2 = 0; k2 < 2; k2++){
        int vd = vb*16 + lr;
        int ck = (k2*4 + g) ^ (vd & 7);
        bf16x8 bv = *reinterpret_cast<const bf16x8*>(&Vs[buf][vd*64 + ck*8]);
        ovb[0][vb] = __builtin_amdgcn_mfma_f32_16x16x32_bf16(ap[0][k2], bv, ovb[0][vb], 0,0,0);
        ovb[1][vb] = __builtin_amdgcn_mfma_f32_16x16x32_bf16(ap[1][k2], bv, ovb[1][vb], 0,0,0);
      }
    __builtin_amdgcn_s_setprio(0);

    if (notlast) __syncthreads();  // vmcnt(0)+lgkm: staged K & V complete; Vs[buf] reads done
    buf ^= 1;
  }

  // ---- epilogue: broadcast row-sums from lr==0 lanes, normalize, store ----
  #pragma unroll
  for (int qg = 0; qg < 2; qg++){
    float inv[4];
    #pragma unroll
    for (int r = 0; r < 4; r++){
      float sum = __shfl(lp[qg][r], lane & 48, 64);
      inv[r] = 1.0f / sum;
    }
    u16* obase = Oa + ((size_t)b*T + q0 + qg*16)*2048 + h*128;
    #pragma unroll
    for (int vb = 0; vb < 8; vb++)
      #pragma unroll
      for (int r = 0; r < 4; r++)
        obase[(size_t)(g*4 + r)*2048 + vb*16 + lr] = f2bf(ovb[qg][vb][r]*inv[r]);
  }
}

// ---------- launch ----------
extern "C" void kernel_launch(void* const* d_in, const int* in_sizes, int n_in,
                              void* d_out, int out_size, void* d_ws, size_t ws_size,
                              hipStream_t stream){
  const float* hs      = (const float*)d_in[0];
  const float* q_a_w   = (const float*)d_in[1];
  const float* q_a_ln  = (const float*)d_in[2];
  const float* q_b_w   = (const float*)d_in[3];
  const float* kv_a_w  = (const float*)d_in[4];
  const float* kv_a_ln = (const float*)d_in[5];
  const float* kv_b_w  = (const float*)d_in[6];
  const float* o_w     = (const float*)d_in[7];

  char* ws = (char*)d_ws;
  size_t off = 0;
  auto alloc = [&](size_t bytes){ void* p = ws + off; off += bytes; return p; };
  u16*  Wqa   = (u16*)alloc(1536ull*2048*2);
  u16*  Wqb   = (u16*)alloc(3072ull*1536*2);
  u16*  Wkva  = (u16*)alloc(1024ull*2048*2);
  u16*  Wkvb  = (u16*)alloc(2048ull*512*2);
  u16*  Wo    = (u16*)alloc(2048ull*2048*2);
  u16*  XB    = (u16*)alloc(4096ull*2048*2);      // x bf16 -> later attn output
  char* R2    = (char*)alloc(4096ull*1536*4);     // q_a fp32 -> later q bf16 [4096][3072]
  char* R3    = (char*)alloc(4096ull*1024*4);     // kv_raw fp32 -> later kv bf16 [4096][2048]
  u16*  Qlat  = (u16*)alloc(4096ull*1536*2);
  u16*  KVlat = (u16*)alloc(4096ull*512*2);
  u16*  Kf    = (u16*)alloc(2ull*8*2048*192*2);
  u16*  Vt    = (u16*)alloc(2ull*8*128*2048*2);
  float* cosT = (float*)alloc(2048ull*32*4);
  float* sinT = (float*)alloc(2048ull*32*4);
  (void)ws_size; (void)in_sizes; (void)n_in; (void)out_size;

  const float qscale = 0.07216878364870322f;      // 192^-0.5 folded into q_b gemm

  cvt_f32_bf16<<<8192, 256, 0, stream>>>(hs, XB, 4096ll*2048);
  transpose_w<<<dim3(1536/32, 2048/32), dim3(32,8), 0, stream>>>(q_a_w,  Wqa,  2048, 1536);
  transpose_w<<<dim3(3072/32, 1536/32), dim3(32,8), 0, stream>>>(q_b_w,  Wqb,  1536, 3072);
  transpose_w<<<dim3(1024/32, 2048/32), dim3(32,8), 0, stream>>>(kv_a_w, Wkva, 2048, 1024);
  transpose_w<<<dim3(2048/32,  512/32), dim3(32,8), 0, stream>>>(kv_b_w, Wkvb,  512, 2048);
  transpose_w<<<dim3(2048/32, 2048/32), dim3(32,8), 0, stream>>>(o_w,    Wo,   2048, 2048);
  rope_tables<<<256, 256, 0, stream>>>(cosT, sinT);

  gemm_bt<0><<<dim3(12, 32), 256, 0, stream>>>(XB, Wqa,  (float*)R2, 4096, 1536, 2048, 1.0f);
  gemm_bt<0><<<dim3( 8, 32), 256, 0, stream>>>(XB, Wkva, (float*)R3, 4096, 1024, 2048, 1.0f);
  rmsnorm_kernel<<<4096, 256, 0, stream>>>((const float*)R2, q_a_ln, Qlat, 1536);
  kv_split_kernel<<<4096, 256, 0, stream>>>((const float*)R3, kv_a_ln, cosT, sinT, KVlat, Kf);
  gemm_bt<1><<<dim3(24, 32), 256, 0, stream>>>(Qlat, Wqb, (u16*)R2, 4096, 3072, 1536, qscale);
  q_rope_kernel<<<8192, 256, 0, stream>>>((u16*)R2, cosT, sinT);
  gemm_bt<1><<<dim3(16, 32), 256, 0, stream>>>(KVlat, Wkvb, (u16*)R3, 4096, 2048, 512, 1.0f);
  knope_kernel<<<2048, 256, 0, stream>>>((const u16*)R3, Kf);
  v_transpose<<<512, 256, 0, stream>>>((const u16*)R3, Vt);
  attn_kernel<<<512, 256, 0, stream>>>((const u16*)R2, Kf, Vt, XB);
  gemm_bt<0><<<dim3(16, 32), 256, 0, stream>>>(XB, Wo, (float*)d_out, 4096, 2048, 2048, 1.0f);
}

// Round 8
// 416.447 us; speedup vs baseline: 1.5135x; 1.0178x over previous
//
#include <hip/hip_runtime.h>

using u16 = unsigned short;
using u32 = unsigned int;

typedef float f32x4 __attribute__((ext_vector_type(4)));
typedef __bf16 bf16x8 __attribute__((ext_vector_type(8)));
typedef u32 u32x2 __attribute__((ext_vector_type(2)));

// ---------- helpers ----------
__device__ __forceinline__ u16 f2bf(float f){
  u32 u = __builtin_bit_cast(u32, f);
  u32 r = (u + 0x7fffu + ((u >> 16) & 1u)) >> 16;   // RNE
  return (u16)r;
}
__device__ __forceinline__ float bf2f(u16 h){
  u32 u = ((u32)h) << 16;
  return __builtin_bit_cast(float, u);
}
__device__ __forceinline__ void gl2lds16(const void* g, void* l){
  __builtin_amdgcn_global_load_lds((const __attribute__((address_space(1))) u32*)g,
                                   (__attribute__((address_space(3))) u32*)l, 16, 0, 0);
}
__device__ __forceinline__ int swz24(int ck, int r){ return (ck & 24) | ((ck ^ r) & 7); }
__device__ __forceinline__ u32 cvtpk_bf16(float a, float b){
  u32 r; asm("v_cvt_pk_bf16_f32 %0, %1, %2" : "=v"(r) : "v"(a), "v"(b)); return r;
}
__device__ __forceinline__ void mfma16(f32x4& acc, u32x2 a, u32x2 b){
  asm("v_mfma_f32_16x16x16_bf16 %0, %1, %2, %0" : "+v"(acc) : "v"(a), "v"(b));
}

// ---------- elementwise convert x ----------
__global__ __launch_bounds__(256) void cvt_f32_bf16(const float* __restrict__ in,
                                                    u16* __restrict__ out, long n){
  long i = ((long)blockIdx.x*256 + threadIdx.x)*4;
  if (i >= n) return;
  float4 v = *(const float4*)(in + i);
  u16 o[4] = { f2bf(v.x), f2bf(v.y), f2bf(v.z), f2bf(v.w) };
  *(ushort4*)(out + i) = *(ushort4*)o;
}

// ---------- weight transpose+convert: in fp32 [K][N] -> out bf16 [N][K] ----------
__global__ __launch_bounds__(256) void transpose_w(const float* __restrict__ in,
                                                   u16* __restrict__ out, int K, int N){
  __shared__ float tile[32][33];
  int n0 = blockIdx.x*32, k0 = blockIdx.y*32;
  int tx = threadIdx.x, ty = threadIdx.y;
  for (int i = ty; i < 32; i += 8)
    tile[i][tx] = in[(size_t)(k0+i)*N + n0+tx];
  __syncthreads();
  for (int i = ty; i < 32; i += 8)
    out[(size_t)(n0+i)*K + k0+tx] = f2bf(tile[tx][i]);
}

// ---------- rope tables (f64 trig) ----------
__global__ __launch_bounds__(256) void rope_tables(float* __restrict__ cosT, float* __restrict__ sinT){
  int idx = blockIdx.x*256 + threadIdx.x;   // 2048*32
  int t = idx >> 5, d = idx & 31;
  double inv = pow(10000.0, -(double)d / 32.0);
  double a = (double)t * inv;
  cosT[idx] = (float)cos(a);
  sinT[idx] = (float)sin(a);
}

// ---------- m97-style 128x128 bf16 MFMA GEMM, C = A[M][K] * Bt[N][K]^T ----------
template<int OUT_BF16>
__global__ __launch_bounds__(256) void gemm_bt(const u16* __restrict__ A,
                                               const u16* __restrict__ Bt,
                                               void* __restrict__ Cout,
                                               int M, int N, int K, float cscale){
  __shared__ u16 As[128*32];
  __shared__ u16 Bs[128*32];
  const int tid = threadIdx.x, lane = tid & 63, wave = tid >> 6;
  const int m0 = blockIdx.y*128, n0 = blockIdx.x*128;
  const int wm = (wave >> 1)*64, wn = (wave & 1)*64;
  const int g = lane >> 4, lr = lane & 15;
  f32x4 acc[4][4] = {};
  const int sr = (wave*2)*16 + (lane >> 2);
  const int sc = (lane & 3)*8;
  for (int k0 = 0; k0 < K; k0 += 32){
    __syncthreads();
    #pragma unroll
    for (int i = 0; i < 2; i++){
      int c = wave*2 + i;
      int r = sr + i*16;
      gl2lds16(A  + (size_t)(m0+r)*K + k0 + sc, (char*)As + c*1024);
      gl2lds16(Bt + (size_t)(n0+r)*K + k0 + sc, (char*)Bs + c*1024);
    }
    __syncthreads();
    bf16x8 af[4], bfr[4];
    #pragma unroll
    for (int mi = 0; mi < 4; mi++) af[mi]  = *reinterpret_cast<const bf16x8*>(&As[(wm+mi*16+lr)*32 + g*8]);
    #pragma unroll
    for (int ni = 0; ni < 4; ni++) bfr[ni] = *reinterpret_cast<const bf16x8*>(&Bs[(wn+ni*16+lr)*32 + g*8]);
    #pragma unroll
    for (int mi = 0; mi < 4; mi++)
      #pragma unroll
      for (int ni = 0; ni < 4; ni++)
        acc[mi][ni] = __builtin_amdgcn_mfma_f32_16x16x32_bf16(af[mi], bfr[ni], acc[mi][ni], 0,0,0);
  }
  #pragma unroll
  for (int mi = 0; mi < 4; mi++)
    #pragma unroll
    for (int ni = 0; ni < 4; ni++)
      #pragma unroll
      for (int r = 0; r < 4; r++){
        int row = m0 + wm + mi*16 + g*4 + r;
        int col = n0 + wn + ni*16 + lr;
        float v = acc[mi][ni][r];
        if (OUT_BF16) ((u16*)Cout)[(size_t)row*N + col] = f2bf(v*cscale);
        else          ((float*)Cout)[(size_t)row*N + col] = v;
      }
}

// ---------- rmsnorm rows (fp32 in [instride] -> bf16 out [ncols]) ----------
__global__ __launch_bounds__(256) void rmsnorm_kernel(const float* __restrict__ in,
                                                      const float* __restrict__ w,
                                                      u16* __restrict__ out, int ncols, int instride){
  int row = blockIdx.x;
  const float* x = in + (size_t)row*instride;
  float ss = 0.f;
  for (int c = threadIdx.x; c < ncols; c += 256){ float v = x[c]; ss += v*v; }
  #pragma unroll
  for (int m = 1; m < 64; m <<= 1) ss += __shfl_xor(ss, m, 64);
  __shared__ float p[4];
  if ((threadIdx.x & 63) == 0) p[threadIdx.x >> 6] = ss;
  __syncthreads();
  float inv = rsqrtf((p[0]+p[1]+p[2]+p[3]) / (float)ncols + 1e-6f);
  u16* o = out + (size_t)row*ncols;
  for (int c = threadIdx.x; c < ncols; c += 256) o[c] = f2bf(x[c]*inv*w[c]);
}

// ---------- kv split (reads merged R23 [4096][2560], cols 1536..2559) ----------
__global__ __launch_bounds__(256) void kv_split_kernel(const float* __restrict__ kvraw,
                                                       const float* __restrict__ lnw,
                                                       const float* __restrict__ cosT,
                                                       const float* __restrict__ sinT,
                                                       u16* __restrict__ kvlat,
                                                       u16* __restrict__ Kf){
  int row = blockIdx.x;                       // 0..4095
  int t = row & 2047, b = row >> 11;
  const float* x = kvraw + (size_t)row*2560 + 1536;
  float ss = 0.f;
  for (int c = threadIdx.x; c < 512; c += 256){ float v = x[c]; ss += v*v; }
  #pragma unroll
  for (int m = 1; m < 64; m <<= 1) ss += __shfl_xor(ss, m, 64);
  __shared__ float p[4];
  if ((threadIdx.x & 63) == 0) p[threadIdx.x >> 6] = ss;
  __syncthreads();
  float inv = rsqrtf((p[0]+p[1]+p[2]+p[3]) / 512.0f + 1e-6f);
  for (int c = threadIdx.x; c < 512; c += 256)
    kvlat[(size_t)row*512 + c] = f2bf(x[c]*inv*lnw[c]);
  int kh = threadIdx.x >> 5, dp = threadIdx.x & 31;
  float x1 = x[512 + kh*64 + dp], x2 = x[512 + kh*64 + dp + 32];
  float cv = cosT[t*32 + dp], sv = sinT[t*32 + dp];
  float o1 = x1*cv - x2*sv;
  float o2 = x2*cv + x1*sv;
  u16* kr = Kf + ((size_t)(b*8 + kh)*2048 + t)*192;
  int c1 = 128 + dp, c2 = 128 + dp + 32;
  kr[(swz24(c1 >> 3, t) << 3) | (c1 & 7)] = f2bf(o1);
  kr[(swz24(c2 >> 3, t) << 3) | (c2 & 7)] = f2bf(o2);
}

// ---------- q rope in place on q bf16 [4096][3072] ----------
__global__ __launch_bounds__(256) void q_rope_kernel(u16* __restrict__ q,
                                                     const float* __restrict__ cosT,
                                                     const float* __restrict__ sinT){
  int idx = blockIdx.x*256 + threadIdx.x;
  int row = idx >> 9, rem = idx & 511;
  int h = rem >> 5, dp = rem & 31;
  int t = row & 2047;
  u16* pq = q + (size_t)row*3072 + h*192 + 128;
  float x1 = bf2f(pq[dp]), x2 = bf2f(pq[dp+32]);
  float cv = cosT[t*32 + dp], sv = sinT[t*32 + dp];
  pq[dp]    = f2bf(x1*cv - x2*sv);
  pq[dp+32] = f2bf(x2*cv + x1*sv);
}

// ---------- k_nope copy (16B chunks, swizzled) ----------
__global__ __launch_bounds__(256) void knope_kernel(const u16* __restrict__ kv,
                                                    u16* __restrict__ Kf){
  int idx = blockIdx.x*256 + threadIdx.x;
  int row = idx >> 7, rem = idx & 127;
  int kh = rem >> 4, ck = rem & 15;
  int t = row & 2047, b = row >> 11;
  int ck2 = (ck & 8) | ((ck ^ t) & 7);
  uint4 v = *(const uint4*)(kv + (size_t)row*2048 + kh*256 + ck*8);
  *(uint4*)(Kf + ((size_t)(b*8 + kh)*2048 + t)*192 + ck2*8) = v;
}

// ---------- V transpose: kv[row][kvh*256+128+vd] -> vT[b][kvh][vd][t] (t-chunks swizzled) ----------
__global__ __launch_bounds__(256) void v_transpose(const u16* __restrict__ kv,
                                                   u16* __restrict__ vT){
  int bid = blockIdx.x;
  int tt = bid & 31, kvh = (bid >> 5) & 7, b = bid >> 8;
  int t0 = tt*64;
  __shared__ u16 tile[64][136];
  int tid = threadIdx.x;
  #pragma unroll
  for (int i = 0; i < 4; i++){
    int c = tid + i*256;
    int r = c >> 4, ck = c & 15;
    const u16* src = kv + ((size_t)(b*2048 + t0 + r))*2048 + kvh*256 + 128 + ck*8;
    *(uint4*)&tile[r][ck*8] = *(const uint4*)src;
  }
  __syncthreads();
  #pragma unroll
  for (int i = 0; i < 4; i++){
    int c = tid + i*256;
    int vd = c >> 3, tc = c & 7;
    int stc = tc ^ (vd & 7);
    uint4 tv;
    u16* tp = (u16*)&tv;
    #pragma unroll
    for (int j = 0; j < 8; j++) tp[j] = tile[tc*8 + j][vd];
    *(uint4*)(vT + ((size_t)(b*8 + kvh)*128 + vd)*2048 + t0 + stc*8) = tv;
  }
}

// ---------- flash attention: swapped-QK, in-register softmax, PV via 16x16x16 MFMA ----------
// Q PRE-SCALED by 192^-0.5. XCD-grouped. LDS 40KB (Ks 24 + Vs 16), 2 q-groups/wave.
__global__ __launch_bounds__(256, 3) void attn_kernel(const u16* __restrict__ Q,
                                                      const u16* __restrict__ Kf,
                                                      const u16* __restrict__ Vt,
                                                      u16* __restrict__ Oa){
  constexpr int T = 2048;
  constexpr int NT = T/64;
  __shared__ u16 Ks[64*192];       // 24KB
  __shared__ u16 Vs[128*64];       // 16KB
  const int tid = threadIdx.x, lane = tid & 63, wave = tid >> 6;
  const int g = lane >> 4, lr = lane & 15;

  // bijective XCD swizzle: all 32 blocks of one (b,kvh) group land on one XCD
  const int wg = blockIdx.x;                 // 0..511
  const int role = (wg & 7)*64 + (wg >> 3);
  const int grp = role >> 5;                 // b*8 + kvh
  const int b = grp >> 3, kvh = grp & 7;
  const int within = role & 31;
  const int h = kvh*2 + (within >> 4);
  const int q0 = (within & 15)*128 + wave*32;

  bf16x8 aq[2][6];
  #pragma unroll
  for (int qg = 0; qg < 2; qg++){
    const u16* qrow = Q + ((size_t)b*T + q0 + qg*16 + lr)*3072 + h*192;
    #pragma unroll
    for (int kc = 0; kc < 6; kc++)
      aq[qg][kc] = *reinterpret_cast<const bf16x8*>(qrow + kc*32 + g*8);
  }
  const u16* Kbase = Kf + (size_t)(b*8 + kvh)*T*192;
  const u16* Vbase = Vt + (size_t)(b*8 + kvh)*128*T;

  f32x4 ovb[2][8] = {};
  float mq[2] = {-1e30f, -1e30f};  // running max for q=lr (uniform across g)
  float lq[2] = {0.f, 0.f};        // running sum for q=lr

  auto stageK = [&](int kt){
    const u16* ksrc = Kbase + (size_t)kt*12288 + wave*3072 + lane*8;
    #pragma unroll
    for (int i = 0; i < 6; i++)
      gl2lds16(ksrc + i*512, (char*)Ks + (wave*6 + i)*1024);
  };
  auto stageV = [&](int kt){
    #pragma unroll
    for (int i = 0; i < 4; i++){
      int c = wave*4 + i;
      const u16* vsrc = Vbase + (size_t)(c*8 + (lane >> 3))*T + kt*64 + (lane & 7)*8;
      gl2lds16(vsrc, (char*)Vs + c*1024);
    }
  };

  stageK(0);
  stageV(0);
  __syncthreads();               // vmcnt(0): K & V tile 0 ready

  for (int kt = 0; kt < NT; kt++){
    const bool notlast = (kt + 1 < NT);

    // ---- QK^T swapped: S[kv][q] = mfma(K, Q); lane (g,lr) reg r = S[nb*16+g*4+r][q=lr] ----
    f32x4 s[2][4];
    __builtin_amdgcn_s_setprio(1);
    #pragma unroll
    for (int nb = 0; nb < 4; nb++){
      const int row = nb*16 + lr;
      f32x4 a0 = {0.f,0.f,0.f,0.f}, a1 = {0.f,0.f,0.f,0.f};
      #pragma unroll
      for (int kc = 0; kc < 6; kc++){
        int ckl = swz24(kc*4 + g, row);
        bf16x8 kf = *reinterpret_cast<const bf16x8*>(&Ks[row*192 + ckl*8]);
        a0 = __builtin_amdgcn_mfma_f32_16x16x32_bf16(kf, aq[0][kc], a0, 0,0,0);
        a1 = __builtin_amdgcn_mfma_f32_16x16x32_bf16(kf, aq[1][kc], a1, 0,0,0);
      }
      s[0][nb] = a0; s[1][nb] = a1;
    }
    __builtin_amdgcn_s_setprio(0);

    __syncthreads();               // K reads done wave-wide; drains V(kt) DMA
    if (notlast) stageK(kt + 1);   // next K DMA; hidden under softmax+PV

    // ---- in-register softmax per q-group (state per lane, q = lr) ----
    u32 pk[2][4][2];
    #pragma unroll
    for (int qg = 0; qg < 2; qg++){
      float pm = s[qg][0][0];
      #pragma unroll
      for (int nb = 0; nb < 4; nb++)
        #pragma unroll
        for (int r = 0; r < 4; r++)
          if (nb || r) pm = fmaxf(pm, s[qg][nb][r]);
      pm = fmaxf(pm, __shfl_xor(pm, 16, 64));
      pm = fmaxf(pm, __shfl_xor(pm, 32, 64));
      if (!__all(pm <= mq[qg] + 8.f)){
        float mn = fmaxf(mq[qg], pm);
        float corr = __expf(mq[qg] - mn);
        mq[qg] = mn;
        lq[qg] *= corr;
        #pragma unroll
        for (int r = 0; r < 4; r++){
          float cr = __shfl(corr, (lane & 48) | (g*4 + r), 64);
          #pragma unroll
          for (int vb = 0; vb < 8; vb++) ovb[qg][vb][r] *= cr;
        }
      }
      float ls = 0.f;
      #pragma unroll
      for (int nb = 0; nb < 4; nb++){
        float e0 = __expf(s[qg][nb][0] - mq[qg]);
        float e1 = __expf(s[qg][nb][1] - mq[qg]);
        float e2 = __expf(s[qg][nb][2] - mq[qg]);
        float e3 = __expf(s[qg][nb][3] - mq[qg]);
        ls += (e0 + e1) + (e2 + e3);
        pk[qg][nb][0] = cvtpk_bf16(e0, e1);
        pk[qg][nb][1] = cvtpk_bf16(e2, e3);
      }
      ls += __shfl_xor(ls, 16, 64);
      ls += __shfl_xor(ls, 32, 64);
      lq[qg] += ls;
    }

    // ---- PV: A = P (lane-local pk), B = V from LDS; 16x16x16 MFMA, K=16 per nb ----
    __builtin_amdgcn_s_setprio(1);
    const int vsw = lr & 7;          // vd & 7, same for all vb
    #pragma unroll
    for (int vb = 0; vb < 8; vb++){
      const int vd = vb*16 + lr;
      #pragma unroll
      for (int nb = 0; nb < 4; nb++){
        int ck = (nb*2 + (g >> 1)) ^ vsw;
        u32x2 bv = *reinterpret_cast<const u32x2*>(&Vs[vd*64 + ck*8 + (g & 1)*4]);
        u32x2 pa0; pa0.x = pk[0][nb][0]; pa0.y = pk[0][nb][1];
        u32x2 pa1; pa1.x = pk[1][nb][0]; pa1.y = pk[1][nb][1];
        mfma16(ovb[0][vb], pa0, bv);
        mfma16(ovb[1][vb], pa1, bv);
      }
    }
    __builtin_amdgcn_s_setprio(0);

    if (notlast){
      __syncthreads();             // V reads done wave-wide; drains K(kt+1) DMA
      stageV(kt + 1);              // next V DMA; hidden under next QK^T
    }
  }

  // ---- epilogue: per-lane 1/l broadcast to O rows, normalize, store ----
  #pragma unroll
  for (int qg = 0; qg < 2; qg++){
    float invq = 1.0f / lq[qg];
    float inv_r[4];
    #pragma unroll
    for (int r = 0; r < 4; r++)
      inv_r[r] = __shfl(invq, (lane & 48) | (g*4 + r), 64);
    u16* obase = Oa + ((size_t)b*T + q0 + qg*16)*2048 + h*128;
    #pragma unroll
    for (int vb = 0; vb < 8; vb++)
      #pragma unroll
      for (int r = 0; r < 4; r++)
        obase[(size_t)(g*4 + r)*2048 + vb*16 + lr] = f2bf(ovb[qg][vb][r]*inv_r[r]);
  }
}

// ---------- launch ----------
extern "C" void kernel_launch(void* const* d_in, const int* in_sizes, int n_in,
                              void* d_out, int out_size, void* d_ws, size_t ws_size,
                              hipStream_t stream){
  const float* hs      = (const float*)d_in[0];
  const float* q_a_w   = (const float*)d_in[1];
  const float* q_a_ln  = (const float*)d_in[2];
  const float* q_b_w   = (const float*)d_in[3];
  const float* kv_a_w  = (const float*)d_in[4];
  const float* kv_a_ln = (const float*)d_in[5];
  const float* kv_b_w  = (const float*)d_in[6];
  const float* o_w     = (const float*)d_in[7];

  char* ws = (char*)d_ws;
  size_t off = 0;
  auto alloc = [&](size_t bytes){ void* p = ws + off; off += bytes; return p; };
  u16*  Wqa   = (u16*)alloc(1536ull*2048*2);      // adjacent: merged [2560][2048]
  u16*  Wkva  = (u16*)alloc(1024ull*2048*2);
  u16*  Wqb   = (u16*)alloc(3072ull*1536*2);
  u16*  Wkvb  = (u16*)alloc(2048ull*512*2);
  u16*  Wo    = (u16*)alloc(2048ull*2048*2);
  u16*  XB    = (u16*)alloc(4096ull*2048*2);      // x bf16 -> later attn output
  char* R23   = (char*)alloc(4096ull*2560*4);     // merged q_a|kv_a fp32 -> later QB/KVB bf16
  u16*  Qlat  = (u16*)alloc(4096ull*1536*2);
  u16*  KVlat = (u16*)alloc(4096ull*512*2);
  u16*  Kf    = (u16*)alloc(2ull*8*2048*192*2);
  u16*  Vt    = (u16*)alloc(2ull*8*128*2048*2);
  float* cosT = (float*)alloc(2048ull*32*4);
  float* sinT = (float*)alloc(2048ull*32*4);
  (void)ws_size; (void)in_sizes; (void)n_in; (void)out_size;

  u16* QB  = (u16*)R23;                           // 4096x3072 bf16 (24MB)
  u16* KVB = (u16*)(R23 + 4096ull*3072*2);        // 4096x2048 bf16 (16MB)

  const float qscale = 0.07216878364870322f;      // 192^-0.5 folded into q_b gemm

  cvt_f32_bf16<<<8192, 256, 0, stream>>>(hs, XB, 4096ll*2048);
  transpose_w<<<dim3(1536/32, 2048/32), dim3(32,8), 0, stream>>>(q_a_w,  Wqa,  2048, 1536);
  transpose_w<<<dim3(1024/32, 2048/32), dim3(32,8), 0, stream>>>(kv_a_w, Wkva, 2048, 1024);
  transpose_w<<<dim3(3072/32, 1536/32), dim3(32,8), 0, stream>>>(q_b_w,  Wqb,  1536, 3072);
  transpose_w<<<dim3(2048/32,  512/32), dim3(32,8), 0, stream>>>(kv_b_w, Wkvb,  512, 2048);
  transpose_w<<<dim3(2048/32, 2048/32), dim3(32,8), 0, stream>>>(o_w,    Wo,   2048, 2048);
  rope_tables<<<256, 256, 0, stream>>>(cosT, sinT);

  // merged q_a + kv_a: N = 1536 + 1024 = 2560
  gemm_bt<0><<<dim3(20, 32), 256, 0, stream>>>(XB, Wqa, (float*)R23, 4096, 2560, 2048, 1.0f);
  rmsnorm_kernel<<<4096, 256, 0, stream>>>((const float*)R23, q_a_ln, Qlat, 1536, 2560);
  kv_split_kernel<<<4096, 256, 0, stream>>>((const float*)R23, kv_a_ln, cosT, sinT, KVlat, Kf);
  gemm_bt<1><<<dim3(24, 32), 256, 0, stream>>>(Qlat, Wqb, QB, 4096, 3072, 1536, qscale);
  q_rope_kernel<<<8192, 256, 0, stream>>>(QB, cosT, sinT);
  gemm_bt<1><<<dim3(16, 32), 256, 0, stream>>>(KVlat, Wkvb, KVB, 4096, 2048, 512, 1.0f);
  knope_kernel<<<2048, 256, 0, stream>>>(KVB, Kf);
  v_transpose<<<512, 256, 0, stream>>>(KVB, Vt);
  attn_kernel<<<512, 256, 0, stream>>>(QB, Kf, Vt, XB);
  gemm_bt<0><<<dim3(16, 32), 256, 0, stream>>>(XB, Wo, (float*)d_out, 4096, 2048, 2048, 1.0f);
}

// Round 9
// 371.427 us; speedup vs baseline: 1.6969x; 1.1212x over previous
//
#include <hip/hip_runtime.h>

using u16 = unsigned short;
using u32 = unsigned int;

typedef float f32x4 __attribute__((ext_vector_type(4)));
typedef __bf16 bf16x8 __attribute__((ext_vector_type(8)));

// ---------- helpers ----------
__device__ __forceinline__ u16 f2bf(float f){
  u32 u = __builtin_bit_cast(u32, f);
  u32 r = (u + 0x7fffu + ((u >> 16) & 1u)) >> 16;   // RNE
  return (u16)r;
}
__device__ __forceinline__ float bf2f(u16 h){
  u32 u = ((u32)h) << 16;
  return __builtin_bit_cast(float, u);
}
__device__ __forceinline__ void gl2lds16(const void* g, void* l){
  __builtin_amdgcn_global_load_lds((const __attribute__((address_space(1))) u32*)g,
                                   (__attribute__((address_space(3))) u32*)l, 16, 0, 0);
}
__device__ __forceinline__ int swz24(int ck, int r){ return (ck & 24) | ((ck ^ r) & 7); }
__device__ __forceinline__ u32 cvtpk_bf16(float a, float b){
  u32 r; asm("v_cvt_pk_bf16_f32 %0, %1, %2" : "=v"(r) : "v"(a), "v"(b)); return r;
}

// ---------- elementwise convert x ----------
__global__ __launch_bounds__(256) void cvt_f32_bf16(const float* __restrict__ in,
                                                    u16* __restrict__ out, long n){
  long i = ((long)blockIdx.x*256 + threadIdx.x)*4;
  if (i >= n) return;
  float4 v = *(const float4*)(in + i);
  u16 o[4] = { f2bf(v.x), f2bf(v.y), f2bf(v.z), f2bf(v.w) };
  *(ushort4*)(out + i) = *(ushort4*)o;
}

// ---------- weight transpose+convert: in fp32 [K][N] -> out bf16 [N][K] ----------
__global__ __launch_bounds__(256) void transpose_w(const float* __restrict__ in,
                                                   u16* __restrict__ out, int K, int N){
  __shared__ float tile[32][33];
  int n0 = blockIdx.x*32, k0 = blockIdx.y*32;
  int tx = threadIdx.x, ty = threadIdx.y;
  for (int i = ty; i < 32; i += 8)
    tile[i][tx] = in[(size_t)(k0+i)*N + n0+tx];
  __syncthreads();
  for (int i = ty; i < 32; i += 8)
    out[(size_t)(n0+i)*K + k0+tx] = f2bf(tile[tx][i]);
}

// ---------- rope tables (f64 trig) ----------
__global__ __launch_bounds__(256) void rope_tables(float* __restrict__ cosT, float* __restrict__ sinT){
  int idx = blockIdx.x*256 + threadIdx.x;   // 2048*32
  int t = idx >> 5, d = idx & 31;
  double inv = pow(10000.0, -(double)d / 32.0);
  double a = (double)t * inv;
  cosT[idx] = (float)cos(a);
  sinT[idx] = (float)sin(a);
}

// ---------- m97-style 128x128 bf16 MFMA GEMM, C = A[M][K] * Bt[N][K]^T ----------
template<int OUT_BF16>
__global__ __launch_bounds__(256) void gemm_bt(const u16* __restrict__ A,
                                               const u16* __restrict__ Bt,
                                               void* __restrict__ Cout,
                                               int M, int N, int K, float cscale){
  __shared__ u16 As[128*32];
  __shared__ u16 Bs[128*32];
  const int tid = threadIdx.x, lane = tid & 63, wave = tid >> 6;
  const int m0 = blockIdx.y*128, n0 = blockIdx.x*128;
  const int wm = (wave >> 1)*64, wn = (wave & 1)*64;
  const int g = lane >> 4, lr = lane & 15;
  f32x4 acc[4][4] = {};
  const int sr = (wave*2)*16 + (lane >> 2);
  const int sc = (lane & 3)*8;
  for (int k0 = 0; k0 < K; k0 += 32){
    __syncthreads();
    #pragma unroll
    for (int i = 0; i < 2; i++){
      int c = wave*2 + i;
      int r = sr + i*16;
      gl2lds16(A  + (size_t)(m0+r)*K + k0 + sc, (char*)As + c*1024);
      gl2lds16(Bt + (size_t)(n0+r)*K + k0 + sc, (char*)Bs + c*1024);
    }
    __syncthreads();
    bf16x8 af[4], bfr[4];
    #pragma unroll
    for (int mi = 0; mi < 4; mi++) af[mi]  = *reinterpret_cast<const bf16x8*>(&As[(wm+mi*16+lr)*32 + g*8]);
    #pragma unroll
    for (int ni = 0; ni < 4; ni++) bfr[ni] = *reinterpret_cast<const bf16x8*>(&Bs[(wn+ni*16+lr)*32 + g*8]);
    #pragma unroll
    for (int mi = 0; mi < 4; mi++)
      #pragma unroll
      for (int ni = 0; ni < 4; ni++)
        acc[mi][ni] = __builtin_amdgcn_mfma_f32_16x16x32_bf16(af[mi], bfr[ni], acc[mi][ni], 0,0,0);
  }
  #pragma unroll
  for (int mi = 0; mi < 4; mi++)
    #pragma unroll
    for (int ni = 0; ni < 4; ni++)
      #pragma unroll
      for (int r = 0; r < 4; r++){
        int row = m0 + wm + mi*16 + g*4 + r;
        int col = n0 + wn + ni*16 + lr;
        float v = acc[mi][ni][r];
        if (OUT_BF16) ((u16*)Cout)[(size_t)row*N + col] = f2bf(v*cscale);
        else          ((float*)Cout)[(size_t)row*N + col] = v;
      }
}

// ---------- rmsnorm rows (fp32 in [instride] -> bf16 out [ncols]) ----------
__global__ __launch_bounds__(256) void rmsnorm_kernel(const float* __restrict__ in,
                                                      const float* __restrict__ w,
                                                      u16* __restrict__ out, int ncols, int instride){
  int row = blockIdx.x;
  const float* x = in + (size_t)row*instride;
  float ss = 0.f;
  for (int c = threadIdx.x; c < ncols; c += 256){ float v = x[c]; ss += v*v; }
  #pragma unroll
  for (int m = 1; m < 64; m <<= 1) ss += __shfl_xor(ss, m, 64);
  __shared__ float p[4];
  if ((threadIdx.x & 63) == 0) p[threadIdx.x >> 6] = ss;
  __syncthreads();
  float inv = rsqrtf((p[0]+p[1]+p[2]+p[3]) / (float)ncols + 1e-6f);
  u16* o = out + (size_t)row*ncols;
  for (int c = threadIdx.x; c < ncols; c += 256) o[c] = f2bf(x[c]*inv*w[c]);
}

// ---------- kv split (reads merged R23 [4096][2560], cols 1536..2559) ----------
__global__ __launch_bounds__(256) void kv_split_kernel(const float* __restrict__ kvraw,
                                                       const float* __restrict__ lnw,
                                                       const float* __restrict__ cosT,
                                                       const float* __restrict__ sinT,
                                                       u16* __restrict__ kvlat,
                                                       u16* __restrict__ Kf){
  int row = blockIdx.x;                       // 0..4095
  int t = row & 2047, b = row >> 11;
  const float* x = kvraw + (size_t)row*2560 + 1536;
  float ss = 0.f;
  for (int c = threadIdx.x; c < 512; c += 256){ float v = x[c]; ss += v*v; }
  #pragma unroll
  for (int m = 1; m < 64; m <<= 1) ss += __shfl_xor(ss, m, 64);
  __shared__ float p[4];
  if ((threadIdx.x & 63) == 0) p[threadIdx.x >> 6] = ss;
  __syncthreads();
  float inv = rsqrtf((p[0]+p[1]+p[2]+p[3]) / 512.0f + 1e-6f);
  for (int c = threadIdx.x; c < 512; c += 256)
    kvlat[(size_t)row*512 + c] = f2bf(x[c]*inv*lnw[c]);
  int kh = threadIdx.x >> 5, dp = threadIdx.x & 31;
  float x1 = x[512 + kh*64 + dp], x2 = x[512 + kh*64 + dp + 32];
  float cv = cosT[t*32 + dp], sv = sinT[t*32 + dp];
  float o1 = x1*cv - x2*sv;
  float o2 = x2*cv + x1*sv;
  u16* kr = Kf + ((size_t)(b*8 + kh)*2048 + t)*192;
  int c1 = 128 + dp, c2 = 128 + dp + 32;
  kr[(swz24(c1 >> 3, t) << 3) | (c1 & 7)] = f2bf(o1);
  kr[(swz24(c2 >> 3, t) << 3) | (c2 & 7)] = f2bf(o2);
}

// ---------- q rope in place on q bf16 [4096][3072] ----------
__global__ __launch_bounds__(256) void q_rope_kernel(u16* __restrict__ q,
                                                     const float* __restrict__ cosT,
                                                     const float* __restrict__ sinT){
  int idx = blockIdx.x*256 + threadIdx.x;
  int row = idx >> 9, rem = idx & 511;
  int h = rem >> 5, dp = rem & 31;
  int t = row & 2047;
  u16* pq = q + (size_t)row*3072 + h*192 + 128;
  float x1 = bf2f(pq[dp]), x2 = bf2f(pq[dp+32]);
  float cv = cosT[t*32 + dp], sv = sinT[t*32 + dp];
  pq[dp]    = f2bf(x1*cv - x2*sv);
  pq[dp+32] = f2bf(x2*cv + x1*sv);
}

// ---------- k_nope copy (16B chunks, swizzled) ----------
__global__ __launch_bounds__(256) void knope_kernel(const u16* __restrict__ kv,
                                                    u16* __restrict__ Kf){
  int idx = blockIdx.x*256 + threadIdx.x;
  int row = idx >> 7, rem = idx & 127;
  int kh = rem >> 4, ck = rem & 15;
  int t = row & 2047, b = row >> 11;
  int ck2 = (ck & 8) | ((ck ^ t) & 7);
  uint4 v = *(const uint4*)(kv + (size_t)row*2048 + kh*256 + ck*8);
  *(uint4*)(Kf + ((size_t)(b*8 + kh)*2048 + t)*192 + ck2*8) = v;
}

// ---------- V transpose: kv[row][kvh*256+128+vd] -> vT[b][kvh][vd][t] (t-chunks swizzled) ----------
__global__ __launch_bounds__(256) void v_transpose(const u16* __restrict__ kv,
                                                   u16* __restrict__ vT){
  int bid = blockIdx.x;
  int tt = bid & 31, kvh = (bid >> 5) & 7, b = bid >> 8;
  int t0 = tt*64;
  __shared__ u16 tile[64][136];
  int tid = threadIdx.x;
  #pragma unroll
  for (int i = 0; i < 4; i++){
    int c = tid + i*256;
    int r = c >> 4, ck = c & 15;
    const u16* src = kv + ((size_t)(b*2048 + t0 + r))*2048 + kvh*256 + 128 + ck*8;
    *(uint4*)&tile[r][ck*8] = *(const uint4*)src;
  }
  __syncthreads();
  #pragma unroll
  for (int i = 0; i < 4; i++){
    int c = tid + i*256;
    int vd = c >> 3, tc = c & 7;
    int stc = tc ^ (vd & 7);
    uint4 tv;
    u16* tp = (u16*)&tv;
    #pragma unroll
    for (int j = 0; j < 8; j++) tp[j] = tile[tc*8 + j][vd];
    *(uint4*)(vT + ((size_t)(b*8 + kvh)*128 + vd)*2048 + t0 + stc*8) = tv;
  }
}

// ---------- flash attention: swapped-QK in-reg softmax + R7 PV (Ps transposed store) ----------
// Q PRE-SCALED by 192^-0.5. XCD-grouped. 2 q-groups/wave, single-K + double-V LDS pipeline.
__global__ __launch_bounds__(256, 2) void attn_kernel(const u16* __restrict__ Q,
                                                      const u16* __restrict__ Kf,
                                                      const u16* __restrict__ Vt,
                                                      u16* __restrict__ Oa){
  constexpr int T = 2048;
  constexpr int NT = T/64;
  __shared__ u16 Ks[64*192];       // 24KB single buffer
  __shared__ u16 Vs[2][128*64];    // 32KB double buffer
  __shared__ u16 Ps[4][2048];      // 16KB: per wave, 2 qg x (16 q x 64 kv)
  const int tid = threadIdx.x, lane = tid & 63, wave = tid >> 6;
  const int g = lane >> 4, lr = lane & 15;

  // bijective XCD swizzle: all 32 blocks of one (b,kvh) group land on one XCD
  const int wg = blockIdx.x;                 // 0..511
  const int role = (wg & 7)*64 + (wg >> 3);
  const int grp = role >> 5;                 // b*8 + kvh
  const int b = grp >> 3, kvh = grp & 7;
  const int within = role & 31;
  const int h = kvh*2 + (within >> 4);
  const int q0 = (within & 15)*128 + wave*32;

  bf16x8 aq[2][6];
  #pragma unroll
  for (int qg = 0; qg < 2; qg++){
    const u16* qrow = Q + ((size_t)b*T + q0 + qg*16 + lr)*3072 + h*192;
    #pragma unroll
    for (int kc = 0; kc < 6; kc++)
      aq[qg][kc] = *reinterpret_cast<const bf16x8*>(qrow + kc*32 + g*8);
  }
  const u16* Kbase = Kf + (size_t)(b*8 + kvh)*T*192;
  const u16* Vbase = Vt + (size_t)(b*8 + kvh)*128*T;

  f32x4 ovb[2][8] = {};
  float mq[2] = {-1e30f, -1e30f};  // running max for q=lr (uniform across g)
  float lq[2] = {0.f, 0.f};        // running sum for q=lr

  auto stageK = [&](int kt){
    const u16* ksrc = Kbase + (size_t)kt*12288 + wave*3072 + lane*8;
    #pragma unroll
    for (int i = 0; i < 6; i++)
      gl2lds16(ksrc + i*512, (char*)Ks + (wave*6 + i)*1024);
  };
  auto stageV = [&](int kt, int buf){
    #pragma unroll
    for (int i = 0; i < 4; i++){
      int c = wave*4 + i;
      const u16* vsrc = Vbase + (size_t)(c*8 + (lane >> 3))*T + kt*64 + (lane & 7)*8;
      gl2lds16(vsrc, (char*)(&Vs[0][0]) + buf*16384 + c*1024);
    }
  };

  stageK(0);
  stageV(0, 0);
  __syncthreads();               // vmcnt(0) drain: K & V tile 0 ready

  int buf = 0;
  for (int kt = 0; kt < NT; kt++){
    const bool notlast = (kt + 1 < NT);

    // prefetch next V into other buffer; hidden under QK+softmax+PV
    if (notlast) stageV(kt + 1, buf ^ 1);

    // ---- QK^T swapped: S[kv][q] = mfma(K, Q); lane (g,lr) reg r = S[nb*16+g*4+r][q=lr] ----
    f32x4 s[2][4];
    __builtin_amdgcn_s_setprio(1);
    #pragma unroll
    for (int nb = 0; nb < 4; nb++){
      const int row = nb*16 + lr;
      f32x4 a0 = {0.f,0.f,0.f,0.f}, a1 = {0.f,0.f,0.f,0.f};
      #pragma unroll
      for (int kc = 0; kc < 6; kc++){
        int ckl = swz24(kc*4 + g, row);
        bf16x8 kf = *reinterpret_cast<const bf16x8*>(&Ks[row*192 + ckl*8]);
        a0 = __builtin_amdgcn_mfma_f32_16x16x32_bf16(kf, aq[0][kc], a0, 0,0,0);
        a1 = __builtin_amdgcn_mfma_f32_16x16x32_bf16(kf, aq[1][kc], a1, 0,0,0);
      }
      s[0][nb] = a0; s[1][nb] = a1;
    }
    __builtin_amdgcn_s_setprio(0);

    // barrier_A: all waves done reading Ks. lgkm-only (V prefetch stays in flight).
    asm volatile("s_waitcnt lgkmcnt(0)" ::: "memory");
    __builtin_amdgcn_s_barrier();
    __builtin_amdgcn_sched_barrier(0);
    if (notlast) stageK(kt + 1);   // DMA next K into same buffer; hidden under softmax+PV

    // ---- in-register softmax (per lane, q=lr); P -> Ps transposed, R7 layout ----
    #pragma unroll
    for (int qg = 0; qg < 2; qg++){
      float pm = s[qg][0][0];
      #pragma unroll
      for (int nb = 0; nb < 4; nb++)
        #pragma unroll
        for (int r = 0; r < 4; r++)
          if (nb || r) pm = fmaxf(pm, s[qg][nb][r]);
      pm = fmaxf(pm, __shfl_xor(pm, 16, 64));
      pm = fmaxf(pm, __shfl_xor(pm, 32, 64));
      if (!__all(pm <= mq[qg] + 8.f)){
        float mn = fmaxf(mq[qg], pm);
        float corr = __expf(mq[qg] - mn);
        mq[qg] = mn;
        lq[qg] *= corr;
        #pragma unroll
        for (int r = 0; r < 4; r++){
          float cr = __shfl(corr, (lane & 48) | (g*4 + r), 64);
          #pragma unroll
          for (int vb = 0; vb < 8; vb++) ovb[qg][vb][r] *= cr;
        }
      }
      float ls = 0.f;
      #pragma unroll
      for (int nb = 0; nb < 4; nb++){
        float e0 = __expf(s[qg][nb][0] - mq[qg]);
        float e1 = __expf(s[qg][nb][1] - mq[qg]);
        float e2 = __expf(s[qg][nb][2] - mq[qg]);
        float e3 = __expf(s[qg][nb][3] - mq[qg]);
        ls += (e0 + e1) + (e2 + e3);
        // store P[q=lr][kv=nb*16+g*4+r] at Ps[q*64 + ((kv>>3)^(q&7))*8 + (kv&7)]
        int stc = (2*nb + (g >> 1)) ^ (lr & 7);
        volatile u32* p = (volatile u32*)&Ps[wave][qg*1024 + lr*64 + stc*8 + (g & 1)*4];
        p[0] = cvtpk_bf16(e0, e1);     // kv&7 = (g&1)*4 + {0,1}
        p[1] = cvtpk_bf16(e2, e3);     // kv&7 = (g&1)*4 + {2,3}
      }
      ls += __shfl_xor(ls, 16, 64);
      ls += __shfl_xor(ls, 32, 64);
      lq[qg] += ls;
    }

    // wave-local LDS write->read fence (Ps is per-wave private)
    asm volatile("s_waitcnt lgkmcnt(0)" ::: "memory");
    __builtin_amdgcn_sched_barrier(0);

    // ---- PV (R7 proven path): A = P from Ps b128, B = V from Vs[buf] b128 ----
    bf16x8 ap[2][2];
    #pragma unroll
    for (int qg = 0; qg < 2; qg++)
      #pragma unroll
      for (int k2 = 0; k2 < 2; k2++){
        int ck = (k2*4 + g) ^ (lr & 7);
        ap[qg][k2] = *reinterpret_cast<const bf16x8*>(&Ps[wave][qg*1024 + lr*64 + ck*8]);
      }
    __builtin_amdgcn_s_setprio(1);
    #pragma unroll
    for (int vb = 0; vb < 8; vb++)
      #pragma unroll
      for (int k2 = 0; k2 < 2; k2++){
        int vd = vb*16 + lr;
        int ck = (k2*4 + g) ^ (vd & 7);
        bf16x8 bv = *reinterpret_cast<const bf16x8*>(&Vs[buf][vd*64 + ck*8]);
        ovb[0][vb] = __builtin_amdgcn_mfma_f32_16x16x32_bf16(ap[0][k2], bv, ovb[0][vb], 0,0,0);
        ovb[1][vb] = __builtin_amdgcn_mfma_f32_16x16x32_bf16(ap[1][k2], bv, ovb[1][vb], 0,0,0);
      }
    __builtin_amdgcn_s_setprio(0);

    if (notlast) __syncthreads();  // vmcnt(0)+lgkm: staged K & V complete; Vs[buf] reads done
    buf ^= 1;
  }

  // ---- epilogue: per-lane 1/l broadcast to O rows, normalize, store ----
  #pragma unroll
  for (int qg = 0; qg < 2; qg++){
    float invq = 1.0f / lq[qg];
    float inv_r[4];
    #pragma unroll
    for (int r = 0; r < 4; r++)
      inv_r[r] = __shfl(invq, (lane & 48) | (g*4 + r), 64);
    u16* obase = Oa + ((size_t)b*T + q0 + qg*16)*2048 + h*128;
    #pragma unroll
    for (int vb = 0; vb < 8; vb++)
      #pragma unroll
      for (int r = 0; r < 4; r++)
        obase[(size_t)(g*4 + r)*2048 + vb*16 + lr] = f2bf(ovb[qg][vb][r]*inv_r[r]);
  }
}

// ---------- launch ----------
extern "C" void kernel_launch(void* const* d_in, const int* in_sizes, int n_in,
                              void* d_out, int out_size, void* d_ws, size_t ws_size,
                              hipStream_t stream){
  const float* hs      = (const float*)d_in[0];
  const float* q_a_w   = (const float*)d_in[1];
  const float* q_a_ln  = (const float*)d_in[2];
  const float* q_b_w   = (const float*)d_in[3];
  const float* kv_a_w  = (const float*)d_in[4];
  const float* kv_a_ln = (const float*)d_in[5];
  const float* kv_b_w  = (const float*)d_in[6];
  const float* o_w     = (const float*)d_in[7];

  char* ws = (char*)d_ws;
  size_t off = 0;
  auto alloc = [&](size_t bytes){ void* p = ws + off; off += bytes; return p; };
  u16*  Wqa   = (u16*)alloc(1536ull*2048*2);      // adjacent: merged [2560][2048]
  u16*  Wkva  = (u16*)alloc(1024ull*2048*2);
  u16*  Wqb   = (u16*)alloc(3072ull*1536*2);
  u16*  Wkvb  = (u16*)alloc(2048ull*512*2);
  u16*  Wo    = (u16*)alloc(2048ull*2048*2);
  u16*  XB    = (u16*)alloc(4096ull*2048*2);      // x bf16 -> later attn output
  char* R23   = (char*)alloc(4096ull*2560*4);     // merged q_a|kv_a fp32 -> later QB/KVB bf16
  u16*  Qlat  = (u16*)alloc(4096ull*1536*2);
  u16*  KVlat = (u16*)alloc(4096ull*512*2);
  u16*  Kf    = (u16*)alloc(2ull*8*2048*192*2);
  u16*  Vt    = (u16*)alloc(2ull*8*128*2048*2);
  float* cosT = (float*)alloc(2048ull*32*4);
  float* sinT = (float*)alloc(2048ull*32*4);
  (void)ws_size; (void)in_sizes; (void)n_in; (void)out_size;

  u16* QB  = (u16*)R23;                           // 4096x3072 bf16 (24MB)
  u16* KVB = (u16*)(R23 + 4096ull*3072*2);        // 4096x2048 bf16 (16MB)

  const float qscale = 0.07216878364870322f;      // 192^-0.5 folded into q_b gemm

  cvt_f32_bf16<<<8192, 256, 0, stream>>>(hs, XB, 4096ll*2048);
  transpose_w<<<dim3(1536/32, 2048/32), dim3(32,8), 0, stream>>>(q_a_w,  Wqa,  2048, 1536);
  transpose_w<<<dim3(1024/32, 2048/32), dim3(32,8), 0, stream>>>(kv_a_w, Wkva, 2048, 1024);
  transpose_w<<<dim3(3072/32, 1536/32), dim3(32,8), 0, stream>>>(q_b_w,  Wqb,  1536, 3072);
  transpose_w<<<dim3(2048/32,  512/32), dim3(32,8), 0, stream>>>(kv_b_w, Wkvb,  512, 2048);
  transpose_w<<<dim3(2048/32, 2048/32), dim3(32,8), 0, stream>>>(o_w,    Wo,   2048, 2048);
  rope_tables<<<256, 256, 0, stream>>>(cosT, sinT);

  // merged q_a + kv_a: N = 1536 + 1024 = 2560
  gemm_bt<0><<<dim3(20, 32), 256, 0, stream>>>(XB, Wqa, (float*)R23, 4096, 2560, 2048, 1.0f);
  rmsnorm_kernel<<<4096, 256, 0, stream>>>((const float*)R23, q_a_ln, Qlat, 1536, 2560);
  kv_split_kernel<<<4096, 256, 0, stream>>>((const float*)R23, kv_a_ln, cosT, sinT, KVlat, Kf);
  gemm_bt<1><<<dim3(24, 32), 256, 0, stream>>>(Qlat, Wqb, QB, 4096, 3072, 1536, qscale);
  q_rope_kernel<<<8192, 256, 0, stream>>>(QB, cosT, sinT);
  gemm_bt<1><<<dim3(16, 32), 256, 0, stream>>>(KVlat, Wkvb, KVB, 4096, 2048, 512, 1.0f);
  knope_kernel<<<2048, 256, 0, stream>>>(KVB, Kf);
  v_transpose<<<512, 256, 0, stream>>>(KVB, Vt);
  attn_kernel<<<512, 256, 0, stream>>>(QB, Kf, Vt, XB);
  gemm_bt<0><<<dim3(16, 32), 256, 0, stream>>>(XB, Wo, (float*)d_out, 4096, 2048, 2048, 1.0f);
}

// Round 10
// 348.458 us; speedup vs baseline: 1.8088x; 1.0659x over previous
//
#include <hip/hip_runtime.h>

using u16 = unsigned short;
using u32 = unsigned int;

typedef float f32x4 __attribute__((ext_vector_type(4)));
typedef __bf16 bf16x8 __attribute__((ext_vector_type(8)));

// ---------- helpers ----------
__device__ __forceinline__ u16 f2bf(float f){
  u32 u = __builtin_bit_cast(u32, f);
  u32 r = (u + 0x7fffu + ((u >> 16) & 1u)) >> 16;   // RNE
  return (u16)r;
}
__device__ __forceinline__ float bf2f(u16 h){
  u32 u = ((u32)h) << 16;
  return __builtin_bit_cast(float, u);
}
__device__ __forceinline__ void gl2lds16(const void* g, void* l){
  __builtin_amdgcn_global_load_lds((const __attribute__((address_space(1))) u32*)g,
                                   (__attribute__((address_space(3))) u32*)l, 16, 0, 0);
}
__device__ __forceinline__ int swz24(int ck, int r){ return (ck & 24) | ((ck ^ r) & 7); }
__device__ __forceinline__ u32 cvtpk_bf16(float a, float b){
  u32 r; asm("v_cvt_pk_bf16_f32 %0, %1, %2" : "=v"(r) : "v"(a), "v"(b)); return r;
}

// ---------- elementwise convert x ----------
__global__ __launch_bounds__(256) void cvt_f32_bf16(const float* __restrict__ in,
                                                    u16* __restrict__ out, long n){
  long i = ((long)blockIdx.x*256 + threadIdx.x)*4;
  if (i >= n) return;
  float4 v = *(const float4*)(in + i);
  u16 o[4] = { f2bf(v.x), f2bf(v.y), f2bf(v.z), f2bf(v.w) };
  *(ushort4*)(out + i) = *(ushort4*)o;
}

// ---------- weight transpose+convert: in fp32 [K][N] -> out bf16 [N][K] ----------
__global__ __launch_bounds__(256) void transpose_w(const float* __restrict__ in,
                                                   u16* __restrict__ out, int K, int N){
  __shared__ float tile[32][33];
  int n0 = blockIdx.x*32, k0 = blockIdx.y*32;
  int tx = threadIdx.x, ty = threadIdx.y;
  for (int i = ty; i < 32; i += 8)
    tile[i][tx] = in[(size_t)(k0+i)*N + n0+tx];
  __syncthreads();
  for (int i = ty; i < 32; i += 8)
    out[(size_t)(n0+i)*K + k0+tx] = f2bf(tile[tx][i]);
}

// ---------- rope tables (f64 trig) ----------
__global__ __launch_bounds__(256) void rope_tables(float* __restrict__ cosT, float* __restrict__ sinT){
  int idx = blockIdx.x*256 + threadIdx.x;   // 2048*32
  int t = idx >> 5, d = idx & 31;
  double inv = pow(10000.0, -(double)d / 32.0);
  double a = (double)t * inv;
  cosT[idx] = (float)cos(a);
  sinT[idx] = (float)sin(a);
}

// ---------- block remap: XCD-grouped, 4 M-panels share each B-panel per XCD ----------
__device__ __forceinline__ void remap_block(int NX, int& bx, int& by){
  int id = blockIdx.y*NX + blockIdx.x;
  bx = id >> 5;
  by = ((id & 7) << 2) | ((id >> 3) & 3);
}

// ---------- m97-style 128x128 bf16 MFMA GEMM, C = A[M][K] * Bt[N][K]^T ----------
template<int OUT_BF16>
__global__ __launch_bounds__(256) void gemm_bt(const u16* __restrict__ A,
                                               const u16* __restrict__ Bt,
                                               void* __restrict__ Cout,
                                               int M, int N, int K, float cscale){
  __shared__ u16 As[128*32];
  __shared__ u16 Bs[128*32];
  const int tid = threadIdx.x, lane = tid & 63, wave = tid >> 6;
  int bx, by; remap_block(gridDim.x, bx, by);
  const int m0 = by*128, n0 = bx*128;
  const int wm = (wave >> 1)*64, wn = (wave & 1)*64;
  const int g = lane >> 4, lr = lane & 15;
  f32x4 acc[4][4] = {};
  const int sr = (wave*2)*16 + (lane >> 2);
  const int sc = (lane & 3)*8;
  for (int k0 = 0; k0 < K; k0 += 32){
    __syncthreads();
    #pragma unroll
    for (int i = 0; i < 2; i++){
      int c = wave*2 + i;
      int r = sr + i*16;
      gl2lds16(A  + (size_t)(m0+r)*K + k0 + sc, (char*)As + c*1024);
      gl2lds16(Bt + (size_t)(n0+r)*K + k0 + sc, (char*)Bs + c*1024);
    }
    __syncthreads();
    bf16x8 af[4], bfr[4];
    #pragma unroll
    for (int mi = 0; mi < 4; mi++) af[mi]  = *reinterpret_cast<const bf16x8*>(&As[(wm+mi*16+lr)*32 + g*8]);
    #pragma unroll
    for (int ni = 0; ni < 4; ni++) bfr[ni] = *reinterpret_cast<const bf16x8*>(&Bs[(wn+ni*16+lr)*32 + g*8]);
    #pragma unroll
    for (int mi = 0; mi < 4; mi++)
      #pragma unroll
      for (int ni = 0; ni < 4; ni++)
        acc[mi][ni] = __builtin_amdgcn_mfma_f32_16x16x32_bf16(af[mi], bfr[ni], acc[mi][ni], 0,0,0);
  }
  #pragma unroll
  for (int mi = 0; mi < 4; mi++)
    #pragma unroll
    for (int ni = 0; ni < 4; ni++)
      #pragma unroll
      for (int r = 0; r < 4; r++){
        int row = m0 + wm + mi*16 + g*4 + r;
        int col = n0 + wn + ni*16 + lr;
        float v = acc[mi][ni][r];
        if (OUT_BF16) ((u16*)Cout)[(size_t)row*N + col] = f2bf(v*cscale);
        else          ((float*)Cout)[(size_t)row*N + col] = v;
      }
}

// ---------- q_b GEMM with fused RoPE + qscale. M=4096,N=3072,K=1536 ----------
__global__ __launch_bounds__(256) void gemm_qb_rope(const u16* __restrict__ A,
                                                    const u16* __restrict__ Bt,
                                                    u16* __restrict__ C,
                                                    const float* __restrict__ cosT,
                                                    const float* __restrict__ sinT){
  constexpr int N = 3072, K = 1536;
  constexpr float qscale = 0.07216878364870322f;   // 192^-0.5
  __shared__ u16 As[128*32];
  __shared__ u16 Bs[128*32];
  const int tid = threadIdx.x, lane = tid & 63, wave = tid >> 6;
  int bx, by; remap_block(gridDim.x, bx, by);
  const int m0 = by*128, n0 = bx*128;
  const int wm = (wave >> 1)*64, wn = (wave & 1)*64;
  const int g = lane >> 4, lr = lane & 15;
  f32x4 acc[4][4] = {};
  const int sr = (wave*2)*16 + (lane >> 2);
  const int sc = (lane & 3)*8;
  for (int k0 = 0; k0 < K; k0 += 32){
    __syncthreads();
    #pragma unroll
    for (int i = 0; i < 2; i++){
      int c = wave*2 + i;
      int r = sr + i*16;
      gl2lds16(A  + (size_t)(m0+r)*K + k0 + sc, (char*)As + c*1024);
      gl2lds16(Bt + (size_t)(n0+r)*K + k0 + sc, (char*)Bs + c*1024);
    }
    __syncthreads();
    bf16x8 af[4], bfr[4];
    #pragma unroll
    for (int mi = 0; mi < 4; mi++) af[mi]  = *reinterpret_cast<const bf16x8*>(&As[(wm+mi*16+lr)*32 + g*8]);
    #pragma unroll
    for (int ni = 0; ni < 4; ni++) bfr[ni] = *reinterpret_cast<const bf16x8*>(&Bs[(wn+ni*16+lr)*32 + g*8]);
    #pragma unroll
    for (int mi = 0; mi < 4; mi++)
      #pragma unroll
      for (int ni = 0; ni < 4; ni++)
        acc[mi][ni] = __builtin_amdgcn_mfma_f32_16x16x32_bf16(af[mi], bfr[ni], acc[mi][ni], 0,0,0);
  }
  // epilogue: rope 64-block iff ((col>>6) % 3) == 2 (uniform per wn half)
  const bool rope = (((n0 + wn) >> 6) % 3) == 2;
  #pragma unroll
  for (int mi = 0; mi < 4; mi++)
    #pragma unroll
    for (int r = 0; r < 4; r++){
      int row = m0 + wm + mi*16 + g*4 + r;
      int t = row & 2047;
      u16* crow = C + (size_t)row*N + n0 + wn;
      if (rope){
        #pragma unroll
        for (int np = 0; np < 2; np++){
          int dp = np*16 + lr;
          float x1 = acc[mi][np][r]*qscale, x2 = acc[mi][np+2][r]*qscale;
          float cv = cosT[t*32 + dp], sv = sinT[t*32 + dp];
          crow[dp]      = f2bf(x1*cv - x2*sv);
          crow[dp + 32] = f2bf(x2*cv + x1*sv);
        }
      } else {
        #pragma unroll
        for (int ni = 0; ni < 4; ni++)
          crow[ni*16 + lr] = f2bf(acc[mi][ni][r]*qscale);
      }
    }
}

// ---------- rmsnorm rows (bf16 in [instride] -> bf16 out [ncols]) ----------
__global__ __launch_bounds__(256) void rmsnorm_bf16(const u16* __restrict__ in,
                                                    const float* __restrict__ w,
                                                    u16* __restrict__ out, int ncols, int instride){
  int row = blockIdx.x;
  const u16* x = in + (size_t)row*instride;
  int c = threadIdx.x;               // chunk of 8, ncols/8 <= 256
  float xs[8];
  float ss = 0.f;
  int nch = ncols >> 3;
  if (c < nch){
    ushort4 a = *(const ushort4*)(x + c*8);
    ushort4 bq = *(const ushort4*)(x + c*8 + 4);
    u16 e[8] = {a.x,a.y,a.z,a.w,bq.x,bq.y,bq.z,bq.w};
    #pragma unroll
    for (int j = 0; j < 8; j++){ xs[j] = bf2f(e[j]); ss += xs[j]*xs[j]; }
  }
  #pragma unroll
  for (int m = 1; m < 64; m <<= 1) ss += __shfl_xor(ss, m, 64);
  __shared__ float p[4];
  if ((threadIdx.x & 63) == 0) p[threadIdx.x >> 6] = ss;
  __syncthreads();
  float inv = rsqrtf((p[0]+p[1]+p[2]+p[3]) / (float)ncols + 1e-6f);
  if (c < nch){
    u16 o[8];
    #pragma unroll
    for (int j = 0; j < 8; j++) o[j] = f2bf(xs[j]*inv*w[c*8+j]);
    *(ushort4*)(out + (size_t)row*ncols + c*8)     = *(ushort4*)o;
    *(ushort4*)(out + (size_t)row*ncols + c*8 + 4) = *(ushort4*)(o+4);
  }
}

// ---------- kv split (bf16 in, merged stride 2560, cols 1536..2559) ----------
__global__ __launch_bounds__(256) void kv_split_kernel(const u16* __restrict__ kvraw,
                                                       const float* __restrict__ lnw,
                                                       const float* __restrict__ cosT,
                                                       const float* __restrict__ sinT,
                                                       u16* __restrict__ kvlat,
                                                       u16* __restrict__ Kf){
  int row = blockIdx.x;                       // 0..4095
  int t = row & 2047, b = row >> 11;
  const u16* x = kvraw + (size_t)row*2560 + 1536;
  int c = threadIdx.x;                        // chunk of 4, 512/4 = 128 chunks
  float xs[4];
  float ss = 0.f;
  if (c < 128){
    ushort4 a = *(const ushort4*)(x + c*4);
    u16 e[4] = {a.x,a.y,a.z,a.w};
    #pragma unroll
    for (int j = 0; j < 4; j++){ xs[j] = bf2f(e[j]); ss += xs[j]*xs[j]; }
  }
  #pragma unroll
  for (int m = 1; m < 64; m <<= 1) ss += __shfl_xor(ss, m, 64);
  __shared__ float p[4];
  if ((threadIdx.x & 63) == 0) p[threadIdx.x >> 6] = ss;
  __syncthreads();
  float inv = rsqrtf((p[0]+p[1]+p[2]+p[3]) / 512.0f + 1e-6f);
  if (c < 128){
    u16 o[4];
    #pragma unroll
    for (int j = 0; j < 4; j++) o[j] = f2bf(xs[j]*inv*lnw[c*4+j]);
    *(ushort4*)(kvlat + (size_t)row*512 + c*4) = *(ushort4*)o;
  }
  // rope: 8 heads x 32 pairs = 256 threads exactly
  int kh = threadIdx.x >> 5, dp = threadIdx.x & 31;
  float x1 = bf2f(x[512 + kh*64 + dp]), x2 = bf2f(x[512 + kh*64 + dp + 32]);
  float cv = cosT[t*32 + dp], sv = sinT[t*32 + dp];
  float o1 = x1*cv - x2*sv;
  float o2 = x2*cv + x1*sv;
  u16* kr = Kf + ((size_t)(b*8 + kh)*2048 + t)*192;
  int c1 = 128 + dp, c2 = 128 + dp + 32;
  kr[(swz24(c1 >> 3, t) << 3) | (c1 & 7)] = f2bf(o1);
  kr[(swz24(c2 >> 3, t) << 3) | (c2 & 7)] = f2bf(o2);
}

// ---------- kv rearrange: knope copy -> Kf (swizzled) + V transpose -> vT ----------
__global__ __launch_bounds__(256) void kv_rearrange(const u16* __restrict__ kv,
                                                    u16* __restrict__ vT,
                                                    u16* __restrict__ Kf){
  int bid = blockIdx.x;                        // 2*8*32
  int tt = bid & 31, kvh = (bid >> 5) & 7, b = bid >> 8;
  int t0 = tt*64;
  __shared__ u16 tile[64][136];
  int tid = threadIdx.x;
  // knope: rows t0..t0+63, 16 chunks each
  #pragma unroll
  for (int i = 0; i < 4; i++){
    int c2 = tid + i*256;
    int rr = c2 >> 4, ck = c2 & 15;
    int t = t0 + rr;
    int ck2 = (ck & 8) | ((ck ^ t) & 7);
    uint4 v = *(const uint4*)(kv + ((size_t)(b*2048 + t))*2048 + kvh*256 + ck*8);
    *(uint4*)(Kf + ((size_t)(b*8 + kvh)*2048 + t)*192 + ck2*8) = v;
  }
  // v transpose
  #pragma unroll
  for (int i = 0; i < 4; i++){
    int c = tid + i*256;
    int r = c >> 4, ck = c & 15;
    const u16* src = kv + ((size_t)(b*2048 + t0 + r))*2048 + kvh*256 + 128 + ck*8;
    *(uint4*)&tile[r][ck*8] = *(const uint4*)src;
  }
  __syncthreads();
  #pragma unroll
  for (int i = 0; i < 4; i++){
    int c = tid + i*256;
    int vd = c >> 3, tc = c & 7;
    int stc = tc ^ (vd & 7);
    uint4 tv;
    u16* tp = (u16*)&tv;
    #pragma unroll
    for (int j = 0; j < 8; j++) tp[j] = tile[tc*8 + j][vd];
    *(uint4*)(vT + ((size_t)(b*8 + kvh)*128 + vd)*2048 + t0 + stc*8) = tv;
  }
}

// ---------- flash attention: swapped-QK in-reg softmax + b128 PV (unchanged from R9) ----------
__global__ __launch_bounds__(256, 2) void attn_kernel(const u16* __restrict__ Q,
                                                      const u16* __restrict__ Kf,
                                                      const u16* __restrict__ Vt,
                                                      u16* __restrict__ Oa){
  constexpr int T = 2048;
  constexpr int NT = T/64;
  __shared__ u16 Ks[64*192];
  __shared__ u16 Vs[2][128*64];
  __shared__ u16 Ps[4][2048];
  const int tid = threadIdx.x, lane = tid & 63, wave = tid >> 6;
  const int g = lane >> 4, lr = lane & 15;

  const int wg = blockIdx.x;                 // 0..511
  const int role = (wg & 7)*64 + (wg >> 3);
  const int grp = role >> 5;                 // b*8 + kvh
  const int b = grp >> 3, kvh = grp & 7;
  const int within = role & 31;
  const int h = kvh*2 + (within >> 4);
  const int q0 = (within & 15)*128 + wave*32;

  bf16x8 aq[2][6];
  #pragma unroll
  for (int qg = 0; qg < 2; qg++){
    const u16* qrow = Q + ((size_t)b*T + q0 + qg*16 + lr)*3072 + h*192;
    #pragma unroll
    for (int kc = 0; kc < 6; kc++)
      aq[qg][kc] = *reinterpret_cast<const bf16x8*>(qrow + kc*32 + g*8);
  }
  const u16* Kbase = Kf + (size_t)(b*8 + kvh)*T*192;
  const u16* Vbase = Vt + (size_t)(b*8 + kvh)*128*T;

  f32x4 ovb[2][8] = {};
  float mq[2] = {-1e30f, -1e30f};
  float lq[2] = {0.f, 0.f};

  auto stageK = [&](int kt){
    const u16* ksrc = Kbase + (size_t)kt*12288 + wave*3072 + lane*8;
    #pragma unroll
    for (int i = 0; i < 6; i++)
      gl2lds16(ksrc + i*512, (char*)Ks + (wave*6 + i)*1024);
  };
  auto stageV = [&](int kt, int buf){
    #pragma unroll
    for (int i = 0; i < 4; i++){
      int c = wave*4 + i;
      const u16* vsrc = Vbase + (size_t)(c*8 + (lane >> 3))*T + kt*64 + (lane & 7)*8;
      gl2lds16(vsrc, (char*)(&Vs[0][0]) + buf*16384 + c*1024);
    }
  };

  stageK(0);
  stageV(0, 0);
  __syncthreads();

  int buf = 0;
  for (int kt = 0; kt < NT; kt++){
    const bool notlast = (kt + 1 < NT);
    if (notlast) stageV(kt + 1, buf ^ 1);

    f32x4 s[2][4];
    __builtin_amdgcn_s_setprio(1);
    #pragma unroll
    for (int nb = 0; nb < 4; nb++){
      const int row = nb*16 + lr;
      f32x4 a0 = {0.f,0.f,0.f,0.f}, a1 = {0.f,0.f,0.f,0.f};
      #pragma unroll
      for (int kc = 0; kc < 6; kc++){
        int ckl = swz24(kc*4 + g, row);
        bf16x8 kf = *reinterpret_cast<const bf16x8*>(&Ks[row*192 + ckl*8]);
        a0 = __builtin_amdgcn_mfma_f32_16x16x32_bf16(kf, aq[0][kc], a0, 0,0,0);
        a1 = __builtin_amdgcn_mfma_f32_16x16x32_bf16(kf, aq[1][kc], a1, 0,0,0);
      }
      s[0][nb] = a0; s[1][nb] = a1;
    }
    __builtin_amdgcn_s_setprio(0);

    asm volatile("s_waitcnt lgkmcnt(0)" ::: "memory");
    __builtin_amdgcn_s_barrier();
    __builtin_amdgcn_sched_barrier(0);
    if (notlast) stageK(kt + 1);

    #pragma unroll
    for (int qg = 0; qg < 2; qg++){
      float pm = s[qg][0][0];
      #pragma unroll
      for (int nb = 0; nb < 4; nb++)
        #pragma unroll
        for (int r = 0; r < 4; r++)
          if (nb || r) pm = fmaxf(pm, s[qg][nb][r]);
      pm = fmaxf(pm, __shfl_xor(pm, 16, 64));
      pm = fmaxf(pm, __shfl_xor(pm, 32, 64));
      if (!__all(pm <= mq[qg] + 8.f)){
        float mn = fmaxf(mq[qg], pm);
        float corr = __expf(mq[qg] - mn);
        mq[qg] = mn;
        lq[qg] *= corr;
        #pragma unroll
        for (int r = 0; r < 4; r++){
          float cr = __shfl(corr, (lane & 48) | (g*4 + r), 64);
          #pragma unroll
          for (int vb = 0; vb < 8; vb++) ovb[qg][vb][r] *= cr;
        }
      }
      float ls = 0.f;
      #pragma unroll
      for (int nb = 0; nb < 4; nb++){
        float e0 = __expf(s[qg][nb][0] - mq[qg]);
        float e1 = __expf(s[qg][nb][1] - mq[qg]);
        float e2 = __expf(s[qg][nb][2] - mq[qg]);
        float e3 = __expf(s[qg][nb][3] - mq[qg]);
        ls += (e0 + e1) + (e2 + e3);
        int stc = (2*nb + (g >> 1)) ^ (lr & 7);
        volatile u32* p = (volatile u32*)&Ps[wave][qg*1024 + lr*64 + stc*8 + (g & 1)*4];
        p[0] = cvtpk_bf16(e0, e1);
        p[1] = cvtpk_bf16(e2, e3);
      }
      ls += __shfl_xor(ls, 16, 64);
      ls += __shfl_xor(ls, 32, 64);
      lq[qg] += ls;
    }

    asm volatile("s_waitcnt lgkmcnt(0)" ::: "memory");
    __builtin_amdgcn_sched_barrier(0);

    bf16x8 ap[2][2];
    #pragma unroll
    for (int qg = 0; qg < 2; qg++)
      #pragma unroll
      for (int k2 = 0; k2 < 2; k2++){
        int ck = (k2*4 + g) ^ (lr & 7);
        ap[qg][k2] = *reinterpret_cast<const bf16x8*>(&Ps[wave][qg*1024 + lr*64 + ck*8]);
      }
    __builtin_amdgcn_s_setprio(1);
    #pragma unroll
    for (int vb = 0; vb < 8; vb++)
      #pragma unroll
      for (int k2 = 0; k2 < 2; k2++){
        int vd = vb*16 + lr;
        int ck = (k2*4 + g) ^ (vd & 7);
        bf16x8 bv = *reinterpret_cast<const bf16x8*>(&Vs[buf][vd*64 + ck*8]);
        ovb[0][vb] = __builtin_amdgcn_mfma_f32_16x16x32_bf16(ap[0][k2], bv, ovb[0][vb], 0,0,0);
        ovb[1][vb] = __builtin_amdgcn_mfma_f32_16x16x32_bf16(ap[1][k2], bv, ovb[1][vb], 0,0,0);
      }
    __builtin_amdgcn_s_setprio(0);

    if (notlast) __syncthreads();
    buf ^= 1;
  }

  #pragma unroll
  for (int qg = 0; qg < 2; qg++){
    float invq = 1.0f / lq[qg];
    float inv_r[4];
    #pragma unroll
    for (int r = 0; r < 4; r++)
      inv_r[r] = __shfl(invq, (lane & 48) | (g*4 + r), 64);
    u16* obase = Oa + ((size_t)b*T + q0 + qg*16)*2048 + h*128;
    #pragma unroll
    for (int vb = 0; vb < 8; vb++)
      #pragma unroll
      for (int r = 0; r < 4; r++)
        obase[(size_t)(g*4 + r)*2048 + vb*16 + lr] = f2bf(ovb[qg][vb][r]*inv_r[r]);
  }
}

// ---------- launch ----------
extern "C" void kernel_launch(void* const* d_in, const int* in_sizes, int n_in,
                              void* d_out, int out_size, void* d_ws, size_t ws_size,
                              hipStream_t stream){
  const float* hs      = (const float*)d_in[0];
  const float* q_a_w   = (const float*)d_in[1];
  const float* q_a_ln  = (const float*)d_in[2];
  const float* q_b_w   = (const float*)d_in[3];
  const float* kv_a_w  = (const float*)d_in[4];
  const float* kv_a_ln = (const float*)d_in[5];
  const float* kv_b_w  = (const float*)d_in[6];
  const float* o_w     = (const float*)d_in[7];

  char* ws = (char*)d_ws;
  size_t off = 0;
  auto alloc = [&](size_t bytes){ void* p = ws + off; off += bytes; return p; };
  u16*  Wqa   = (u16*)alloc(1536ull*2048*2);      // adjacent: merged [2560][2048]
  u16*  Wkva  = (u16*)alloc(1024ull*2048*2);
  u16*  Wqb   = (u16*)alloc(3072ull*1536*2);
  u16*  Wkvb  = (u16*)alloc(2048ull*512*2);
  u16*  Wo    = (u16*)alloc(2048ull*2048*2);
  u16*  XB    = (u16*)alloc(4096ull*2048*2);      // x bf16 -> later attn output
  u16*  R23   = (u16*)alloc(4096ull*2560*2);      // merged latents bf16 -> later KVB [4096][2048]
  u16*  QB    = (u16*)alloc(4096ull*3072*2);
  u16*  Qlat  = (u16*)alloc(4096ull*1536*2);
  u16*  KVlat = (u16*)alloc(4096ull*512*2);
  u16*  Kf    = (u16*)alloc(2ull*8*2048*192*2);
  u16*  Vt    = (u16*)alloc(2ull*8*128*2048*2);
  float* cosT = (float*)alloc(2048ull*32*4);
  float* sinT = (float*)alloc(2048ull*32*4);
  (void)ws_size; (void)in_sizes; (void)n_in; (void)out_size;

  u16* KVB = R23;                                 // R23 dead after rmsnorm/kv_split

  cvt_f32_bf16<<<8192, 256, 0, stream>>>(hs, XB, 4096ll*2048);
  transpose_w<<<dim3(1536/32, 2048/32), dim3(32,8), 0, stream>>>(q_a_w,  Wqa,  2048, 1536);
  transpose_w<<<dim3(1024/32, 2048/32), dim3(32,8), 0, stream>>>(kv_a_w, Wkva, 2048, 1024);
  transpose_w<<<dim3(3072/32, 1536/32), dim3(32,8), 0, stream>>>(q_b_w,  Wqb,  1536, 3072);
  transpose_w<<<dim3(2048/32,  512/32), dim3(32,8), 0, stream>>>(kv_b_w, Wkvb,  512, 2048);
  transpose_w<<<dim3(2048/32, 2048/32), dim3(32,8), 0, stream>>>(o_w,    Wo,   2048, 2048);
  rope_tables<<<256, 256, 0, stream>>>(cosT, sinT);

  // merged q_a + kv_a: N = 2560, bf16 out
  gemm_bt<1><<<dim3(20, 32), 256, 0, stream>>>(XB, Wqa, R23, 4096, 2560, 2048, 1.0f);
  rmsnorm_bf16<<<4096, 256, 0, stream>>>(R23, q_a_ln, Qlat, 1536, 2560);
  kv_split_kernel<<<4096, 256, 0, stream>>>(R23, kv_a_ln, cosT, sinT, KVlat, Kf);
  gemm_qb_rope<<<dim3(24, 32), 256, 0, stream>>>(Qlat, Wqb, QB, cosT, sinT);
  gemm_bt<1><<<dim3(16, 32), 256, 0, stream>>>(KVlat, Wkvb, KVB, 4096, 2048, 512, 1.0f);
  kv_rearrange<<<512, 256, 0, stream>>>(KVB, Vt, Kf);
  attn_kernel<<<512, 256, 0, stream>>>(QB, Kf, Vt, XB);
  gemm_bt<0><<<dim3(16, 32), 256, 0, stream>>>(XB, Wo, (float*)d_out, 4096, 2048, 2048, 1.0f);
}